// Round 1
// baseline (3121.573 us; speedup 1.0000x reference)
//
#include <hip/hip_runtime.h>
#include <hip/hip_bf16.h>
#include <math.h>

// Problem constants
#define Bc   2
#define Lc   2048
#define Dc   512
#define DIc  1024
#define Nc   16
#define Kc   4
#define Rc   32
#define CKc  31
#define DFFc 2048
#define Mrows (Bc*Lc)   // 4096

__device__ __forceinline__ float sigmoidf_(float x){ return 1.f/(1.f+expf(-x)); }
__device__ __forceinline__ float siluf_(float x){ return x*sigmoidf_(x); }
__device__ __forceinline__ float softplusf_(float x){ return fmaxf(x,0.f)+log1pf(expf(-fabsf(x))); }
__device__ __forceinline__ float geluf_(float x){
    float x3 = x*x*x;
    return 0.5f*x*(1.f+tanhf(0.7978845608028654f*(x+0.044715f*x3)));
}

// ---------------- LayerNorm (one block per row, D=512) ----------------
__global__ void ln_kernel(const float* __restrict__ in, const float* __restrict__ g,
                          const float* __restrict__ bb, float* __restrict__ out, int D) {
    int row = blockIdx.x;
    const float* x = in + (size_t)row * D;
    float s = 0.f, s2 = 0.f;
    for (int i = threadIdx.x; i < D; i += blockDim.x) { float v = x[i]; s += v; s2 += v*v; }
    #pragma unroll
    for (int off = 32; off; off >>= 1) { s += __shfl_down(s, off); s2 += __shfl_down(s2, off); }
    __shared__ float sh[2][4];
    int wave = threadIdx.x >> 6, lane = threadIdx.x & 63;
    if (lane == 0) { sh[0][wave] = s; sh[1][wave] = s2; }
    __syncthreads();
    if (threadIdx.x == 0) {
        float ts = 0.f, ts2 = 0.f;
        int nw = blockDim.x >> 6;
        for (int w = 0; w < nw; ++w) { ts += sh[0][w]; ts2 += sh[1][w]; }
        sh[0][0] = ts; sh[1][0] = ts2;
    }
    __syncthreads();
    float mean = sh[0][0] / D;
    float var  = sh[1][0] / D - mean*mean;
    float rstd = rsqrtf(var + 1e-5f);
    float* o = out + (size_t)row * D;
    for (int i = threadIdx.x; i < D; i += blockDim.x)
        o[i] = (x[i]-mean)*rstd*g[i] + bb[i];
}

// ---------------- Generic tiled fp32 GEMM: out = act(A@W + bias) (+ res) ----------------
// A: M x K with row stride lda; W: K x N contiguous; out: M x N contiguous.
// ACT: 0 none, 1 softplus, 2 gelu(tanh)
template<int ACT, bool BIAS, bool RES>
__global__ void gemm_kernel(const float* __restrict__ A, int lda,
                            const float* __restrict__ W,
                            const float* __restrict__ bias,
                            const float* __restrict__ res,
                            float* __restrict__ out,
                            int M, int N, int K) {
    __shared__ float As[16][65];
    __shared__ float Bs[16][65];
    int tx = threadIdx.x, ty = threadIdx.y;
    int tid = ty*16 + tx;
    int bm = blockIdx.y*64, bn = blockIdx.x*64;
    float acc[4][4] = {};
    for (int k0 = 0; k0 < K; k0 += 16) {
        #pragma unroll
        for (int i = tid; i < 64*16; i += 256) {
            int r = i >> 4, c = i & 15;
            As[c][r] = A[(size_t)(bm+r)*lda + k0 + c];
        }
        #pragma unroll
        for (int i = tid; i < 16*64; i += 256) {
            int kk = i >> 6, nn = i & 63;
            Bs[kk][nn] = W[(size_t)(k0+kk)*N + bn + nn];
        }
        __syncthreads();
        #pragma unroll
        for (int kk = 0; kk < 16; ++kk) {
            float a[4], b[4];
            #pragma unroll
            for (int i = 0; i < 4; ++i) a[i] = As[kk][ty*4+i];
            #pragma unroll
            for (int j = 0; j < 4; ++j) b[j] = Bs[kk][tx*4+j];
            #pragma unroll
            for (int i = 0; i < 4; ++i)
                #pragma unroll
                for (int j = 0; j < 4; ++j)
                    acc[i][j] = fmaf(a[i], b[j], acc[i][j]);
        }
        __syncthreads();
    }
    #pragma unroll
    for (int i = 0; i < 4; ++i) {
        int row = bm + ty*4 + i;
        #pragma unroll
        for (int j = 0; j < 4; ++j) {
            int col = bn + tx*4 + j;
            float v = acc[i][j];
            if (BIAS) v += bias[col];
            if (ACT == 1) v = softplusf_(v);
            else if (ACT == 2) v = geluf_(v);
            if (RES) v += res[(size_t)row*N + col];
            out[(size_t)row*N + col] = v;
        }
    }
}

// ---------------- causal depthwise conv K=4 + silu: reads xi half of xz ----------------
__global__ void causal_conv_silu(const float* __restrict__ xz, const float* __restrict__ w,
                                 const float* __restrict__ bias, float* __restrict__ xc) {
    int idx = blockIdx.x*blockDim.x + threadIdx.x;
    if (idx >= Bc*Lc*DIc) return;
    int d  = idx & (DIc-1);
    int bl = idx >> 10;          // b*L + l
    int l  = bl & (Lc-1);
    float acc = bias[d];
    #pragma unroll
    for (int k = 0; k < Kc; ++k) {
        int ls = l - (Kc-1) + k;
        if (ls >= 0) acc = fmaf(xz[((size_t)(bl - (Kc-1) + k))*(2*DIc) + d], w[d*Kc + k], acc);
    }
    xc[idx] = siluf_(acc);
}

// ---------------- selective scan: 16 lanes per (b,d) channel, lane = n ----------------
__global__ void scan_kernel(const float* __restrict__ delta, const float* __restrict__ xc,
                            const float* __restrict__ dbl, const float* __restrict__ xz,
                            const float* __restrict__ A_log, const float* __restrict__ Dp,
                            float* __restrict__ y) {
    int tid = threadIdx.x;
    int sub = tid >> 4, n = tid & 15;
    int ch = blockIdx.x * 16 + sub;       // 0..2047
    int b = ch >> 10, d = ch & (DIc-1);
    float Av = -expf(A_log[d*Nc + n]);
    float Dv = Dp[d];
    float hs = 0.f;
    size_t base = (size_t)b * Lc;
    for (int l = 0; l < Lc; ++l) {
        size_t rowi = base + l;
        float dv  = delta[rowi*DIc + d];
        float xcv = xc[rowi*DIc + d];
        float Bv  = dbl[rowi*64 + Rc + n];
        float Cv  = dbl[rowi*64 + Rc + Nc + n];
        hs = fmaf(expf(dv*Av), hs, dv*xcv*Bv);
        float contrib = hs * Cv;
        contrib += __shfl_xor(contrib, 1);
        contrib += __shfl_xor(contrib, 2);
        contrib += __shfl_xor(contrib, 4);
        contrib += __shfl_xor(contrib, 8);
        if (n == 0) {
            float zv = xz[rowi*(2*DIc) + DIc + d];
            y[rowi*DIc + d] = (contrib + Dv*xcv) * siluf_(zv);
        }
    }
}

// ---------------- GLU: a * sigmoid(g), halves of c2 (rows of 1024) ----------------
__global__ void glu_kernel(const float* __restrict__ c2, float* __restrict__ out) {
    int idx = blockIdx.x*blockDim.x + threadIdx.x;
    if (idx >= Bc*Lc*Dc) return;
    int col = idx & (Dc-1); int row = idx >> 9;
    float a  = c2[(size_t)row*(2*Dc) + col];
    float gg = c2[(size_t)row*(2*Dc) + Dc + col];
    out[idx] = a * sigmoidf_(gg);
}

// ---------------- symmetric depthwise conv CK=31 + silu ----------------
__global__ void sym_conv_silu(const float* __restrict__ in, const float* __restrict__ w,
                              const float* __restrict__ bias, float* __restrict__ out) {
    int idx = blockIdx.x*blockDim.x + threadIdx.x;
    if (idx >= Bc*Lc*Dc) return;
    int d  = idx & (Dc-1);
    int bl = idx >> 9;
    int l  = bl & (Lc-1);
    float acc = bias[d];
    #pragma unroll
    for (int k = 0; k < CKc; ++k) {
        int ls = l - (CKc-1)/2 + k;
        if (ls >= 0 && ls < Lc)
            acc = fmaf(in[((size_t)(bl + ls - l))*Dc + d], w[d*CKc + k], acc);
    }
    out[idx] = siluf_(acc);
}

extern "C" void kernel_launch(void* const* d_in, const int* in_sizes, int n_in,
                              void* d_out, int out_size, void* d_ws, size_t ws_size,
                              hipStream_t stream) {
    const float* x      = (const float*)d_in[0];
    const float* ln_g   = (const float*)d_in[1];
    const float* ln_b   = (const float*)d_in[2];
    const float* W_in   = (const float*)d_in[3];
    const float* conv_w = (const float*)d_in[4];
    const float* conv_b = (const float*)d_in[5];
    const float* W_x    = (const float*)d_in[6];
    const float* W_dt   = (const float*)d_in[7];
    const float* b_dt   = (const float*)d_in[8];
    const float* A_log  = (const float*)d_in[9];
    const float* Dp     = (const float*)d_in[10];
    const float* W_out  = (const float*)d_in[11];
    const float* cm_ln_g= (const float*)d_in[12];
    const float* cm_ln_b= (const float*)d_in[13];
    const float* pw1_w  = (const float*)d_in[14];
    const float* pw1_b  = (const float*)d_in[15];
    const float* dw_w   = (const float*)d_in[16];
    const float* dw_b   = (const float*)d_in[17];
    const float* pw2_w  = (const float*)d_in[18];
    const float* pw2_b  = (const float*)d_in[19];
    const float* ff_W1  = (const float*)d_in[20];
    const float* ff_b1  = (const float*)d_in[21];
    const float* ff_W2  = (const float*)d_in[22];
    const float* ff_b2  = (const float*)d_in[23];
    float* out = (float*)d_out;
    float* ws  = (float*)d_ws;

    // Workspace regions (floats). Total 23,330,816 floats = ~93 MB.
    float* bufA = ws;              // 8M: xz, later g1
    float* bufB = ws + 8388608;    // 4M: xc, later c2
    float* bufC = ws + 12582912;   // 256K: dbl
    float* bufD = ws + 12845056;   // 4M: delta, later cconv (lower 2M)
    float* bufE = ws + 17039360;   // 4M: y, later c (lower 2M) + cglu (upper 2M)
    float* bufF = ws + 21233664;   // 2M: h, later m

    float* h_buf   = bufF;
    float* xz_buf  = bufA;
    float* xc_buf  = bufB;
    float* dbl_buf = bufC;
    float* dl_buf  = bufD;
    float* y_buf   = bufE;
    float* m_buf   = bufF;
    float* c_buf   = bufE;
    float* c2_buf  = bufB;
    float* glu_buf = bufE + 2097152;
    float* cc_buf  = bufD;
    float* f_buf   = out;          // f lives in d_out; GEMM8 reads it as residual
    float* g1_buf  = bufA;

    const int M = Mrows;
    dim3 t16(16,16);

    // 1. h = LN(x)
    ln_kernel<<<M, 256, 0, stream>>>(x, ln_g, ln_b, h_buf, Dc);
    // 2. xz = h @ W_in  (4096x512x2048)
    { dim3 g(2*DIc/64, M/64);
      gemm_kernel<0,false,false><<<g,t16,0,stream>>>(h_buf, Dc, W_in, nullptr, nullptr, xz_buf, M, 2*DIc, Dc); }
    // 3. xc = silu(causal dwconv(xi))
    causal_conv_silu<<<(M*DIc+255)/256, 256, 0, stream>>>(xz_buf, conv_w, conv_b, xc_buf);
    // 4. dbl = xc @ W_x  (4096x1024x64)
    { dim3 g(64/64, M/64);
      gemm_kernel<0,false,false><<<g,t16,0,stream>>>(xc_buf, DIc, W_x, nullptr, nullptr, dbl_buf, M, 64, DIc); }
    // 5. delta = softplus(dt @ W_dt + b_dt)  (4096x32x1024), dt strided in dbl
    { dim3 g(DIc/64, M/64);
      gemm_kernel<1,true,false><<<g,t16,0,stream>>>(dbl_buf, 64, W_dt, b_dt, nullptr, dl_buf, M, DIc, Rc); }
    // 6. selective scan -> y (gated by silu(z), +Dp*xc)
    scan_kernel<<<Bc*DIc/16, 256, 0, stream>>>(dl_buf, xc_buf, dbl_buf, xz_buf, A_log, Dp, y_buf);
    // 7. m = y @ W_out  (4096x1024x512)
    { dim3 g(Dc/64, M/64);
      gemm_kernel<0,false,false><<<g,t16,0,stream>>>(y_buf, DIc, W_out, nullptr, nullptr, m_buf, M, Dc, DIc); }
    // 8. c = LN(m, cm)
    ln_kernel<<<M, 256, 0, stream>>>(m_buf, cm_ln_g, cm_ln_b, c_buf, Dc);
    // 9. c2 = c @ pw1 + b  (4096x512x1024)
    { dim3 g(2*Dc/64, M/64);
      gemm_kernel<0,true,false><<<g,t16,0,stream>>>(c_buf, Dc, pw1_w, pw1_b, nullptr, c2_buf, M, 2*Dc, Dc); }
    // 10. GLU
    glu_kernel<<<(M*Dc+255)/256, 256, 0, stream>>>(c2_buf, glu_buf);
    // 11. symmetric dwconv CK=31 + silu
    sym_conv_silu<<<(M*Dc+255)/256, 256, 0, stream>>>(glu_buf, dw_w, dw_b, cc_buf);
    // 12. m = m + (cconv @ pw2 + b)  (4096x512x512)
    { dim3 g(Dc/64, M/64);
      gemm_kernel<0,true,true><<<g,t16,0,stream>>>(cc_buf, Dc, pw2_w, pw2_b, m_buf, m_buf, M, Dc, Dc); }
    // 13. f = LN(m, ln)  -> d_out
    ln_kernel<<<M, 256, 0, stream>>>(m_buf, ln_g, ln_b, f_buf, Dc);
    // 14. g1 = gelu(f @ ff_W1 + b1)  (4096x512x2048)
    { dim3 g(DFFc/64, M/64);
      gemm_kernel<2,true,false><<<g,t16,0,stream>>>(f_buf, Dc, ff_W1, ff_b1, nullptr, g1_buf, M, DFFc, Dc); }
    // 15. out = f + g1 @ ff_W2 + b2  (4096x2048x512)
    { dim3 g(Dc/64, M/64);
      gemm_kernel<0,true,true><<<g,t16,0,stream>>>(g1_buf, DFFc, ff_W2, ff_b2, f_buf, out, M, Dc, DFFc); }
}

// Round 2
// 1600.897 us; speedup vs baseline: 1.9499x; 1.9499x over previous
//
#include <hip/hip_runtime.h>
#include <hip/hip_bf16.h>
#include <math.h>

// Problem constants
#define Bc   2
#define Lc   2048
#define Dc   512
#define DIc  1024
#define Nc   16
#define Kc   4
#define Rc   32
#define CKc  31
#define DFFc 2048
#define Mrows (Bc*Lc)   // 4096
#define CHUNK  128
#define NCHUNK 16

__device__ __forceinline__ float sigmoidf_(float x){ return 1.f/(1.f+expf(-x)); }
__device__ __forceinline__ float siluf_(float x){ return x*sigmoidf_(x); }
__device__ __forceinline__ float softplusf_(float x){ return fmaxf(x,0.f)+log1pf(expf(-fabsf(x))); }
__device__ __forceinline__ float geluf_(float x){
    float x3 = x*x*x;
    return 0.5f*x*(1.f+tanhf(0.7978845608028654f*(x+0.044715f*x3)));
}

// ---------------- LayerNorm (one block per row, D=512) ----------------
__global__ void ln_kernel(const float* __restrict__ in, const float* __restrict__ g,
                          const float* __restrict__ bb, float* __restrict__ out, int D) {
    int row = blockIdx.x;
    const float* x = in + (size_t)row * D;
    float s = 0.f, s2 = 0.f;
    for (int i = threadIdx.x; i < D; i += blockDim.x) { float v = x[i]; s += v; s2 += v*v; }
    #pragma unroll
    for (int off = 32; off; off >>= 1) { s += __shfl_down(s, off); s2 += __shfl_down(s2, off); }
    __shared__ float sh[2][4];
    int wave = threadIdx.x >> 6, lane = threadIdx.x & 63;
    if (lane == 0) { sh[0][wave] = s; sh[1][wave] = s2; }
    __syncthreads();
    if (threadIdx.x == 0) {
        float ts = 0.f, ts2 = 0.f;
        int nw = blockDim.x >> 6;
        for (int w = 0; w < nw; ++w) { ts += sh[0][w]; ts2 += sh[1][w]; }
        sh[0][0] = ts; sh[1][0] = ts2;
    }
    __syncthreads();
    float mean = sh[0][0] / D;
    float var  = sh[1][0] / D - mean*mean;
    float rstd = rsqrtf(var + 1e-5f);
    float* o = out + (size_t)row * D;
    for (int i = threadIdx.x; i < D; i += blockDim.x)
        o[i] = (x[i]-mean)*rstd*g[i] + bb[i];
}

// ---------------- Generic tiled fp32 GEMM: out = act(A@W + bias) (+ res) ----------------
template<int ACT, bool BIAS, bool RES>
__global__ void gemm_kernel(const float* __restrict__ A, int lda,
                            const float* __restrict__ W,
                            const float* __restrict__ bias,
                            const float* __restrict__ res,
                            float* __restrict__ out,
                            int M, int N, int K) {
    __shared__ float As[16][65];
    __shared__ float Bs[16][65];
    int tx = threadIdx.x, ty = threadIdx.y;
    int tid = ty*16 + tx;
    int bm = blockIdx.y*64, bn = blockIdx.x*64;
    float acc[4][4] = {};
    for (int k0 = 0; k0 < K; k0 += 16) {
        #pragma unroll
        for (int i = tid; i < 64*16; i += 256) {
            int r = i >> 4, c = i & 15;
            As[c][r] = A[(size_t)(bm+r)*lda + k0 + c];
        }
        #pragma unroll
        for (int i = tid; i < 16*64; i += 256) {
            int kk = i >> 6, nn = i & 63;
            Bs[kk][nn] = W[(size_t)(k0+kk)*N + bn + nn];
        }
        __syncthreads();
        #pragma unroll
        for (int kk = 0; kk < 16; ++kk) {
            float a[4], b[4];
            #pragma unroll
            for (int i = 0; i < 4; ++i) a[i] = As[kk][ty*4+i];
            #pragma unroll
            for (int j = 0; j < 4; ++j) b[j] = Bs[kk][tx*4+j];
            #pragma unroll
            for (int i = 0; i < 4; ++i)
                #pragma unroll
                for (int j = 0; j < 4; ++j)
                    acc[i][j] = fmaf(a[i], b[j], acc[i][j]);
        }
        __syncthreads();
    }
    #pragma unroll
    for (int i = 0; i < 4; ++i) {
        int row = bm + ty*4 + i;
        #pragma unroll
        for (int j = 0; j < 4; ++j) {
            int col = bn + tx*4 + j;
            float v = acc[i][j];
            if (BIAS) v += bias[col];
            if (ACT == 1) v = softplusf_(v);
            else if (ACT == 2) v = geluf_(v);
            if (RES) v += res[(size_t)row*N + col];
            out[(size_t)row*N + col] = v;
        }
    }
}

// ---------------- causal depthwise conv K=4 + silu ----------------
__global__ void causal_conv_silu(const float* __restrict__ xz, const float* __restrict__ w,
                                 const float* __restrict__ bias, float* __restrict__ xc) {
    int idx = blockIdx.x*blockDim.x + threadIdx.x;
    if (idx >= Bc*Lc*DIc) return;
    int d  = idx & (DIc-1);
    int bl = idx >> 10;          // b*L + l
    int l  = bl & (Lc-1);
    float acc = bias[d];
    #pragma unroll
    for (int k = 0; k < Kc; ++k) {
        int ls = l - (Kc-1) + k;
        if (ls >= 0) acc = fmaf(xz[((size_t)(bl - (Kc-1) + k))*(2*DIc) + d], w[d*Kc + k], acc);
    }
    xc[idx] = siluf_(acc);
}

// ---------------- chunked selective scan ----------------
// Pass 1: per (channel,chunk) compute P = prod(dA), H = local scan from 0.
__global__ void scan_pass1(const float* __restrict__ delta, const float* __restrict__ xc,
                           const float* __restrict__ dbl, const float* __restrict__ A_log,
                           float* __restrict__ P, float* __restrict__ H) {
    int tid = threadIdx.x;
    int sub = tid >> 4, n = tid & 15;
    int pair = blockIdx.x * 16 + sub;      // 0..32767
    int channel = pair & 2047;             // b*DI + d
    int chunk = pair >> 11;
    int b = channel >> 10, d = channel & (DIc-1);
    float Av = -expf(A_log[d*Nc + n]);
    float hs = 0.f, Pa = 1.f;
    size_t base = (size_t)b * Lc + (size_t)chunk*CHUNK;
    for (int i = 0; i < CHUNK; ++i) {
        size_t rowi = base + i;
        float dv  = delta[rowi*DIc + d];
        float xcv = xc[rowi*DIc + d];
        float Bv  = dbl[rowi*64 + Rc + n];
        float a = expf(dv*Av);
        hs = fmaf(a, hs, dv*xcv*Bv);
        Pa *= a;
    }
    size_t idx = (size_t)chunk*32768 + channel*16 + n;
    P[idx] = Pa; H[idx] = hs;
}

// Pass 2: serial combine across chunks per (channel,n); emit prefix h_start per chunk.
__global__ void scan_combine(const float* __restrict__ P, const float* __restrict__ H,
                             float* __restrict__ hstart) {
    int t = blockIdx.x*blockDim.x + threadIdx.x;  // 0..32767 = channel*16+n
    float h = 0.f;
    #pragma unroll
    for (int c = 0; c < NCHUNK; ++c) {
        size_t idx = (size_t)c*32768 + t;
        hstart[idx] = h;
        h = fmaf(P[idx], h, H[idx]);
    }
}

// Pass 3: re-scan each chunk from its prefix, reduce over n, gate, write y.
__global__ void scan_pass3(const float* __restrict__ delta, const float* __restrict__ xc,
                           const float* __restrict__ dbl, const float* __restrict__ xz,
                           const float* __restrict__ A_log, const float* __restrict__ Dp,
                           const float* __restrict__ hstart, float* __restrict__ y) {
    int tid = threadIdx.x;
    int sub = tid >> 4, n = tid & 15;
    int pair = blockIdx.x * 16 + sub;
    int channel = pair & 2047;
    int chunk = pair >> 11;
    int b = channel >> 10, d = channel & (DIc-1);
    float Av = -expf(A_log[d*Nc + n]);
    float Dv = Dp[d];
    float hs = hstart[(size_t)chunk*32768 + channel*16 + n];
    size_t base = (size_t)b * Lc + (size_t)chunk*CHUNK;
    for (int i = 0; i < CHUNK; ++i) {
        size_t rowi = base + i;
        float dv  = delta[rowi*DIc + d];
        float xcv = xc[rowi*DIc + d];
        float Bv  = dbl[rowi*64 + Rc + n];
        float Cv  = dbl[rowi*64 + Rc + Nc + n];
        hs = fmaf(expf(dv*Av), hs, dv*xcv*Bv);
        float contrib = hs * Cv;
        contrib += __shfl_xor(contrib, 1);
        contrib += __shfl_xor(contrib, 2);
        contrib += __shfl_xor(contrib, 4);
        contrib += __shfl_xor(contrib, 8);
        if (n == 0) {
            float zv = xz[rowi*(2*DIc) + DIc + d];
            y[rowi*DIc + d] = (contrib + Dv*xcv) * siluf_(zv);
        }
    }
}

// ---------------- GLU ----------------
__global__ void glu_kernel(const float* __restrict__ c2, float* __restrict__ out) {
    int idx = blockIdx.x*blockDim.x + threadIdx.x;
    if (idx >= Bc*Lc*Dc) return;
    int col = idx & (Dc-1); int row = idx >> 9;
    float a  = c2[(size_t)row*(2*Dc) + col];
    float gg = c2[(size_t)row*(2*Dc) + Dc + col];
    out[idx] = a * sigmoidf_(gg);
}

// ---------------- symmetric depthwise conv CK=31 + silu ----------------
__global__ void sym_conv_silu(const float* __restrict__ in, const float* __restrict__ w,
                              const float* __restrict__ bias, float* __restrict__ out) {
    int idx = blockIdx.x*blockDim.x + threadIdx.x;
    if (idx >= Bc*Lc*Dc) return;
    int d  = idx & (Dc-1);
    int bl = idx >> 9;
    int l  = bl & (Lc-1);
    float acc = bias[d];
    #pragma unroll
    for (int k = 0; k < CKc; ++k) {
        int ls = l - (CKc-1)/2 + k;
        if (ls >= 0 && ls < Lc)
            acc = fmaf(in[((size_t)(bl + ls - l))*Dc + d], w[d*CKc + k], acc);
    }
    out[idx] = siluf_(acc);
}

extern "C" void kernel_launch(void* const* d_in, const int* in_sizes, int n_in,
                              void* d_out, int out_size, void* d_ws, size_t ws_size,
                              hipStream_t stream) {
    const float* x      = (const float*)d_in[0];
    const float* ln_g   = (const float*)d_in[1];
    const float* ln_b   = (const float*)d_in[2];
    const float* W_in   = (const float*)d_in[3];
    const float* conv_w = (const float*)d_in[4];
    const float* conv_b = (const float*)d_in[5];
    const float* W_x    = (const float*)d_in[6];
    const float* W_dt   = (const float*)d_in[7];
    const float* b_dt   = (const float*)d_in[8];
    const float* A_log  = (const float*)d_in[9];
    const float* Dp     = (const float*)d_in[10];
    const float* W_out  = (const float*)d_in[11];
    const float* cm_ln_g= (const float*)d_in[12];
    const float* cm_ln_b= (const float*)d_in[13];
    const float* pw1_w  = (const float*)d_in[14];
    const float* pw1_b  = (const float*)d_in[15];
    const float* dw_w   = (const float*)d_in[16];
    const float* dw_b   = (const float*)d_in[17];
    const float* pw2_w  = (const float*)d_in[18];
    const float* pw2_b  = (const float*)d_in[19];
    const float* ff_W1  = (const float*)d_in[20];
    const float* ff_b1  = (const float*)d_in[21];
    const float* ff_W2  = (const float*)d_in[22];
    const float* ff_b2  = (const float*)d_in[23];
    float* out = (float*)d_out;
    float* ws  = (float*)d_ws;

    // Workspace regions (floats). Total 23,330,816 floats = ~93 MB.
    float* bufA = ws;              // 8M: xz, later g1
    float* bufB = ws + 8388608;    // 4M: xc, later c2
    float* bufC = ws + 12582912;   // 256K: dbl
    float* bufD = ws + 12845056;   // 4M: delta, later cconv (lower 2M)
    float* bufE = ws + 17039360;   // 4M: y, later c (lower 2M) + cglu (upper 2M)
    float* bufF = ws + 21233664;   // 2M: h, then scan P/H/hstart, then m

    float* h_buf   = bufF;
    float* xz_buf  = bufA;
    float* xc_buf  = bufB;
    float* dbl_buf = bufC;
    float* dl_buf  = bufD;
    float* y_buf   = bufE;
    float* m_buf   = bufF;
    float* c_buf   = bufE;
    float* c2_buf  = bufB;
    float* glu_buf = bufE + 2097152;
    float* cc_buf  = bufD;
    float* f_buf   = out;          // f lives in d_out
    float* g1_buf  = bufA;
    // scan scratch lives in bufF (free between GEMM2 and GEMM7): 3 x 512K floats
    float* P_buf  = bufF;
    float* H_buf  = bufF + 524288;
    float* hs_buf = bufF + 1048576;

    const int M = Mrows;
    dim3 t16(16,16);

    // 1. h = LN(x)
    ln_kernel<<<M, 256, 0, stream>>>(x, ln_g, ln_b, h_buf, Dc);
    // 2. xz = h @ W_in  (4096x512x2048)
    { dim3 g(2*DIc/64, M/64);
      gemm_kernel<0,false,false><<<g,t16,0,stream>>>(h_buf, Dc, W_in, nullptr, nullptr, xz_buf, M, 2*DIc, Dc); }
    // 3. xc = silu(causal dwconv(xi))
    causal_conv_silu<<<(M*DIc+255)/256, 256, 0, stream>>>(xz_buf, conv_w, conv_b, xc_buf);
    // 4. dbl = xc @ W_x  (4096x1024x64)
    { dim3 g(64/64, M/64);
      gemm_kernel<0,false,false><<<g,t16,0,stream>>>(xc_buf, DIc, W_x, nullptr, nullptr, dbl_buf, M, 64, DIc); }
    // 5. delta = softplus(dt @ W_dt + b_dt)  (4096x32x1024)
    { dim3 g(DIc/64, M/64);
      gemm_kernel<1,true,false><<<g,t16,0,stream>>>(dbl_buf, 64, W_dt, b_dt, nullptr, dl_buf, M, DIc, Rc); }
    // 6. chunked selective scan -> y
    scan_pass1<<<2048, 256, 0, stream>>>(dl_buf, xc_buf, dbl_buf, A_log, P_buf, H_buf);
    scan_combine<<<128, 256, 0, stream>>>(P_buf, H_buf, hs_buf);
    scan_pass3<<<2048, 256, 0, stream>>>(dl_buf, xc_buf, dbl_buf, xz_buf, A_log, Dp, hs_buf, y_buf);
    // 7. m = y @ W_out  (4096x1024x512)
    { dim3 g(Dc/64, M/64);
      gemm_kernel<0,false,false><<<g,t16,0,stream>>>(y_buf, DIc, W_out, nullptr, nullptr, m_buf, M, Dc, DIc); }
    // 8. c = LN(m, cm)
    ln_kernel<<<M, 256, 0, stream>>>(m_buf, cm_ln_g, cm_ln_b, c_buf, Dc);
    // 9. c2 = c @ pw1 + b  (4096x512x1024)
    { dim3 g(2*Dc/64, M/64);
      gemm_kernel<0,true,false><<<g,t16,0,stream>>>(c_buf, Dc, pw1_w, pw1_b, nullptr, c2_buf, M, 2*Dc, Dc); }
    // 10. GLU
    glu_kernel<<<(M*Dc+255)/256, 256, 0, stream>>>(c2_buf, glu_buf);
    // 11. symmetric dwconv CK=31 + silu
    sym_conv_silu<<<(M*Dc+255)/256, 256, 0, stream>>>(glu_buf, dw_w, dw_b, cc_buf);
    // 12. m = m + (cconv @ pw2 + b)  (4096x512x512)
    { dim3 g(Dc/64, M/64);
      gemm_kernel<0,true,true><<<g,t16,0,stream>>>(cc_buf, Dc, pw2_w, pw2_b, m_buf, m_buf, M, Dc, Dc); }
    // 13. f = LN(m, ln)  -> d_out
    ln_kernel<<<M, 256, 0, stream>>>(m_buf, ln_g, ln_b, f_buf, Dc);
    // 14. g1 = gelu(f @ ff_W1 + b1)  (4096x512x2048)
    { dim3 g(DFFc/64, M/64);
      gemm_kernel<2,true,false><<<g,t16,0,stream>>>(f_buf, Dc, ff_W1, ff_b1, nullptr, g1_buf, M, DFFc, Dc); }
    // 15. out = f + g1 @ ff_W2 + b2  (4096x2048x512)
    { dim3 g(Dc/64, M/64);
      gemm_kernel<0,true,true><<<g,t16,0,stream>>>(g1_buf, DFFc, ff_W2, ff_b2, f_buf, out, M, Dc, DFFc); }
}

// Round 3
// 691.719 us; speedup vs baseline: 4.5128x; 2.3144x over previous
//
#include <hip/hip_runtime.h>
#include <hip/hip_bf16.h>
#include <math.h>

// Problem constants
#define Bc   2
#define Lc   2048
#define Dc   512
#define DIc  1024
#define Nc   16
#define Kc   4
#define Rc   32
#define CKc  31
#define DFFc 2048
#define Mrows (Bc*Lc)   // 4096
#define CHUNK  128
#define NCHUNK 16

typedef __hip_bfloat16 bf16;
typedef short bf16x8 __attribute__((ext_vector_type(8)));
typedef float f32x4  __attribute__((ext_vector_type(4)));

__device__ __forceinline__ float sigmoidf_(float x){ return 1.f/(1.f+expf(-x)); }
__device__ __forceinline__ float siluf_(float x){ return x*sigmoidf_(x); }
__device__ __forceinline__ float softplusf_(float x){ return fmaxf(x,0.f)+log1pf(expf(-fabsf(x))); }
__device__ __forceinline__ float geluf_(float x){
    float x3 = x*x*x;
    return 0.5f*x*(1.f+tanhf(0.7978845608028654f*(x+0.044715f*x3)));
}

// ---------------- LayerNorm (one block per row, D=512); optional f32/bf16 outs ----------------
template<bool WF, bool WB>
__global__ void ln_kernel(const float* __restrict__ in, const float* __restrict__ g,
                          const float* __restrict__ bb, float* __restrict__ outf,
                          bf16* __restrict__ outb, int D) {
    int row = blockIdx.x;
    const float* x = in + (size_t)row * D;
    float s = 0.f, s2 = 0.f;
    for (int i = threadIdx.x; i < D; i += blockDim.x) { float v = x[i]; s += v; s2 += v*v; }
    #pragma unroll
    for (int off = 32; off; off >>= 1) { s += __shfl_down(s, off); s2 += __shfl_down(s2, off); }
    __shared__ float sh[2][4];
    int wave = threadIdx.x >> 6, lane = threadIdx.x & 63;
    if (lane == 0) { sh[0][wave] = s; sh[1][wave] = s2; }
    __syncthreads();
    if (threadIdx.x == 0) {
        float ts = 0.f, ts2 = 0.f;
        int nw = blockDim.x >> 6;
        for (int w = 0; w < nw; ++w) { ts += sh[0][w]; ts2 += sh[1][w]; }
        sh[0][0] = ts; sh[1][0] = ts2;
    }
    __syncthreads();
    float mean = sh[0][0] / D;
    float var  = sh[1][0] / D - mean*mean;
    float rstd = rsqrtf(var + 1e-5f);
    for (int i = threadIdx.x; i < D; i += blockDim.x) {
        float v = (x[i]-mean)*rstd*g[i] + bb[i];
        if (WF) outf[(size_t)row*D + i] = v;
        if (WB) outb[(size_t)row*D + i] = __float2bfloat16(v);
    }
}

// ---------------- weight transpose+cast: W (K x N, f32) -> Wt (N x K, bf16) ----------------
__global__ void wtrans(const float* __restrict__ W, bf16* __restrict__ Wt, int K, int N) {
    __shared__ float t[32][33];
    int bx = blockIdx.x, by = blockIdx.y;
    int tx = threadIdx.x, ty = threadIdx.y;   // 32 x 8
    #pragma unroll
    for (int i = 0; i < 32; i += 8)
        t[ty+i][tx] = W[(size_t)(by*32+ty+i)*N + bx*32+tx];
    __syncthreads();
    #pragma unroll
    for (int i = 0; i < 32; i += 8)
        Wt[(size_t)(bx*32+ty+i)*K + by*32+tx] = __float2bfloat16(t[tx][ty+i]);
}

// ---------------- bf16 MFMA GEMM: out = act(A@B + bias) (+res), B given as Wt = N x K ----------------
// A: M x K bf16, row stride lda. Wt: N x K bf16. 4 waves (2x2), per-wave (BM/2)x(BN/2).
// ACT: 0 none, 1 softplus, 2 gelu. Optional fp32 and/or bf16 outputs.
template<int BM, int BN, int ACT, bool BIAS, bool RES, bool WF32, bool WBF16>
__global__ __launch_bounds__(256) void mgemm(const bf16* __restrict__ A, int lda,
                                             const bf16* __restrict__ Wt,
                                             const float* __restrict__ bias,
                                             const float* __restrict__ res,
                                             float* __restrict__ outf,
                                             bf16* __restrict__ outb,
                                             int M, int N, int K) {
    constexpr int BK = 32;
    constexpr int WM = BM/2, WN = BN/2;       // per-wave tile
    constexpr int AM = WM/16, AN = WN/16;     // frags per wave
    constexpr int AITER = BM/64, BITER = BN/64;
    __shared__ __align__(16) bf16 As[BM*BK];
    __shared__ __align__(16) bf16 Bs[BN*BK];
    const int tid  = threadIdx.x;
    const int wave = tid >> 6, lane = tid & 63;
    const int r16  = lane & 15, kb = lane >> 4;
    const int bm = blockIdx.y*BM, bn = blockIdx.x*BN;
    const int wm = (wave>>1)*WM, wn = (wave&1)*WN;
    f32x4 acc[AM][AN] = {};

    for (int k0 = 0; k0 < K; k0 += BK) {
        uint4 ar[AITER], br[BITER];
        #pragma unroll
        for (int it = 0; it < AITER; ++it) {
            int c = it*256 + tid;
            ar[it] = *(const uint4*)(&A[(size_t)(bm + (c>>2))*lda + k0 + (c&3)*8]);
        }
        #pragma unroll
        for (int it = 0; it < BITER; ++it) {
            int c = it*256 + tid;
            br[it] = *(const uint4*)(&Wt[(size_t)(bn + (c>>2))*K + k0 + (c&3)*8]);
        }
        __syncthreads();   // previous iteration's reads done before overwrite
        #pragma unroll
        for (int it = 0; it < AITER; ++it)
            *(uint4*)(&As[(size_t)(it*256 + tid)*8]) = ar[it];
        #pragma unroll
        for (int it = 0; it < BITER; ++it)
            *(uint4*)(&Bs[(size_t)(it*256 + tid)*8]) = br[it];
        __syncthreads();
        bf16x8 af[AM], bfr[AN];
        #pragma unroll
        for (int mi = 0; mi < AM; ++mi)
            af[mi] = *(const bf16x8*)(&As[(wm + mi*16 + r16)*BK + kb*8]);
        #pragma unroll
        for (int ni = 0; ni < AN; ++ni)
            bfr[ni] = *(const bf16x8*)(&Bs[(wn + ni*16 + r16)*BK + kb*8]);
        #pragma unroll
        for (int mi = 0; mi < AM; ++mi)
            #pragma unroll
            for (int ni = 0; ni < AN; ++ni)
                acc[mi][ni] = __builtin_amdgcn_mfma_f32_16x16x32_bf16(af[mi], bfr[ni], acc[mi][ni], 0, 0, 0);
    }

    // epilogue: C/D map col=lane&15, row=(lane>>4)*4+r
    #pragma unroll
    for (int mi = 0; mi < AM; ++mi) {
        #pragma unroll
        for (int ni = 0; ni < AN; ++ni) {
            #pragma unroll
            for (int r = 0; r < 4; ++r) {
                int grow = bm + wm + mi*16 + kb*4 + r;
                int gcol = bn + wn + ni*16 + r16;
                float v = acc[mi][ni][r];
                if (BIAS) v += bias[gcol];
                if (ACT == 1) v = softplusf_(v);
                else if (ACT == 2) v = geluf_(v);
                if (RES) v += res[(size_t)grow*N + gcol];
                if (WF32)  outf[(size_t)grow*N + gcol] = v;
                if (WBF16) outb[(size_t)grow*N + gcol] = __float2bfloat16(v);
            }
        }
    }
}

// ---------------- causal depthwise conv K=4 + silu; writes f32 + bf16 ----------------
__global__ void causal_conv_silu(const float* __restrict__ xz, const float* __restrict__ w,
                                 const float* __restrict__ bias, float* __restrict__ xc,
                                 bf16* __restrict__ xcb) {
    int idx = blockIdx.x*blockDim.x + threadIdx.x;
    if (idx >= Bc*Lc*DIc) return;
    int d  = idx & (DIc-1);
    int bl = idx >> 10;          // b*L + l
    int l  = bl & (Lc-1);
    float acc = bias[d];
    #pragma unroll
    for (int k = 0; k < Kc; ++k) {
        int ls = l - (Kc-1) + k;
        if (ls >= 0) acc = fmaf(xz[((size_t)(bl - (Kc-1) + k))*(2*DIc) + d], w[d*Kc + k], acc);
    }
    float v = siluf_(acc);
    xc[idx] = v;
    xcb[idx] = __float2bfloat16(v);
}

// ---------------- chunked selective scan ----------------
__global__ void scan_pass1(const float* __restrict__ delta, const float* __restrict__ xc,
                           const float* __restrict__ dbl, const float* __restrict__ A_log,
                           float* __restrict__ P, float* __restrict__ H) {
    int tid = threadIdx.x;
    int sub = tid >> 4, n = tid & 15;
    int pair = blockIdx.x * 16 + sub;      // 0..32767
    int channel = pair & 2047;             // b*DI + d
    int chunk = pair >> 11;
    int b = channel >> 10, d = channel & (DIc-1);
    float Av = -expf(A_log[d*Nc + n]);
    float hs = 0.f, Pa = 1.f;
    size_t base = (size_t)b * Lc + (size_t)chunk*CHUNK;
    for (int i = 0; i < CHUNK; ++i) {
        size_t rowi = base + i;
        float dv  = delta[rowi*DIc + d];
        float xcv = xc[rowi*DIc + d];
        float Bv  = dbl[rowi*64 + Rc + n];
        float a = expf(dv*Av);
        hs = fmaf(a, hs, dv*xcv*Bv);
        Pa *= a;
    }
    size_t idx = (size_t)chunk*32768 + channel*16 + n;
    P[idx] = Pa; H[idx] = hs;
}

__global__ void scan_combine(const float* __restrict__ P, const float* __restrict__ H,
                             float* __restrict__ hstart) {
    int t = blockIdx.x*blockDim.x + threadIdx.x;  // channel*16+n
    float h = 0.f;
    #pragma unroll
    for (int c = 0; c < NCHUNK; ++c) {
        size_t idx = (size_t)c*32768 + t;
        hstart[idx] = h;
        h = fmaf(P[idx], h, H[idx]);
    }
}

__global__ void scan_pass3(const float* __restrict__ delta, const float* __restrict__ xc,
                           const float* __restrict__ dbl, const float* __restrict__ xz,
                           const float* __restrict__ A_log, const float* __restrict__ Dp,
                           const float* __restrict__ hstart, bf16* __restrict__ y) {
    int tid = threadIdx.x;
    int sub = tid >> 4, n = tid & 15;
    int pair = blockIdx.x * 16 + sub;
    int channel = pair & 2047;
    int chunk = pair >> 11;
    int b = channel >> 10, d = channel & (DIc-1);
    float Av = -expf(A_log[d*Nc + n]);
    float Dv = Dp[d];
    float hs = hstart[(size_t)chunk*32768 + channel*16 + n];
    size_t base = (size_t)b * Lc + (size_t)chunk*CHUNK;
    for (int i = 0; i < CHUNK; ++i) {
        size_t rowi = base + i;
        float dv  = delta[rowi*DIc + d];
        float xcv = xc[rowi*DIc + d];
        float Bv  = dbl[rowi*64 + Rc + n];
        float Cv  = dbl[rowi*64 + Rc + Nc + n];
        hs = fmaf(expf(dv*Av), hs, dv*xcv*Bv);
        float contrib = hs * Cv;
        contrib += __shfl_xor(contrib, 1);
        contrib += __shfl_xor(contrib, 2);
        contrib += __shfl_xor(contrib, 4);
        contrib += __shfl_xor(contrib, 8);
        if (n == 0) {
            float zv = xz[rowi*(2*DIc) + DIc + d];
            y[rowi*DIc + d] = __float2bfloat16((contrib + Dv*xcv) * siluf_(zv));
        }
    }
}

// ---------------- GLU ----------------
__global__ void glu_kernel(const float* __restrict__ c2, float* __restrict__ out) {
    int idx = blockIdx.x*blockDim.x + threadIdx.x;
    if (idx >= Bc*Lc*Dc) return;
    int col = idx & (Dc-1); int row = idx >> 9;
    float a  = c2[(size_t)row*(2*Dc) + col];
    float gg = c2[(size_t)row*(2*Dc) + Dc + col];
    out[idx] = a * sigmoidf_(gg);
}

// ---------------- symmetric depthwise conv CK=31 + silu -> bf16 ----------------
__global__ void sym_conv_silu(const float* __restrict__ in, const float* __restrict__ w,
                              const float* __restrict__ bias, bf16* __restrict__ out) {
    int idx = blockIdx.x*blockDim.x + threadIdx.x;
    if (idx >= Bc*Lc*Dc) return;
    int d  = idx & (Dc-1);
    int bl = idx >> 9;
    int l  = bl & (Lc-1);
    float acc = bias[d];
    #pragma unroll
    for (int k = 0; k < CKc; ++k) {
        int ls = l - (CKc-1)/2 + k;
        if (ls >= 0 && ls < Lc)
            acc = fmaf(in[((size_t)(bl + ls - l))*Dc + d], w[d*CKc + k], acc);
    }
    out[idx] = __float2bfloat16(siluf_(acc));
}

extern "C" void kernel_launch(void* const* d_in, const int* in_sizes, int n_in,
                              void* d_out, int out_size, void* d_ws, size_t ws_size,
                              hipStream_t stream) {
    const float* x      = (const float*)d_in[0];
    const float* ln_g   = (const float*)d_in[1];
    const float* ln_b   = (const float*)d_in[2];
    const float* W_in   = (const float*)d_in[3];
    const float* conv_w = (const float*)d_in[4];
    const float* conv_b = (const float*)d_in[5];
    const float* W_x    = (const float*)d_in[6];
    const float* W_dt   = (const float*)d_in[7];
    const float* b_dt   = (const float*)d_in[8];
    const float* A_log  = (const float*)d_in[9];
    const float* Dp     = (const float*)d_in[10];
    const float* W_out  = (const float*)d_in[11];
    const float* cm_ln_g= (const float*)d_in[12];
    const float* cm_ln_b= (const float*)d_in[13];
    const float* pw1_w  = (const float*)d_in[14];
    const float* pw1_b  = (const float*)d_in[15];
    const float* dw_w   = (const float*)d_in[16];
    const float* dw_b   = (const float*)d_in[17];
    const float* pw2_w  = (const float*)d_in[18];
    const float* pw2_b  = (const float*)d_in[19];
    const float* ff_W1  = (const float*)d_in[20];
    const float* ff_b1  = (const float*)d_in[21];
    const float* ff_W2  = (const float*)d_in[22];
    const float* ff_b2  = (const float*)d_in[23];
    float* out = (float*)d_out;
    float* ws  = (float*)d_ws;

    // ---- workspace layout (float offsets), total 22,986,752 floats ~92 MB ----
    float* A_  = ws;                 // 8,388,608: xz -> later c2 [0:4M) + glu [4M:6M)
    float* B_  = ws + 8388608;       // 4,194,304: xc f32 -> later g1_bf16 (as bf16)
    float* C_  = ws + 12582912;      //   262,144: dbl f32
    float* D_  = ws + 12845056;      // 4,194,304: delta -> later m [0:2M)
    float* F_  = ws + 17039360;      // 1,572,864: dbl_bf16 / P,H,hs / c_bf16 / cc_bf16 / f_bf16
    float* H_  = ws + 18612224;      // 2,097,152: h_bf16 / xc_bf16 / y_bf16
    float* J_  = ws + 20709376;      // 2,277,376: transposed bf16 weights

    float* xz_buf  = A_;
    float* c2_buf  = A_;
    float* glu_buf = A_ + 4194304;
    float* xc_buf  = B_;
    bf16*  g1b     = (bf16*)B_;
    float* dbl_buf = C_;
    float* dl_buf  = D_;
    float* m_buf   = D_;
    bf16*  dblb    = (bf16*)F_;
    float* P_buf   = F_;
    float* H_buf   = F_ + 524288;
    float* hs_buf  = F_ + 1048576;
    bf16*  cb      = (bf16*)F_;      // c_bf16, then cc_bf16, then f_bf16 (sequential lifetimes)
    bf16*  ccb     = (bf16*)F_;
    bf16*  fb      = (bf16*)F_;
    bf16*  hb      = (bf16*)H_;
    bf16*  xcb     = (bf16*)H_;
    bf16*  yb      = (bf16*)H_;
    float* f_buf   = out;            // f lives in d_out; GEMM15 reads it as residual

    bf16* Jw = (bf16*)J_;
    bf16* Win_t  = Jw;               // 2048 x 512
    bf16* Wx_t   = Jw + 1048576;     //   64 x 1024
    bf16* Wdt_t  = Jw + 1114112;     // 1024 x 32
    bf16* Wout_t = Jw + 1146880;     //  512 x 1024
    bf16* pw1_t  = Jw + 1671168;     // 1024 x 512
    bf16* pw2_t  = Jw + 2195456;     //  512 x 512
    bf16* ffW1_t = Jw + 2457600;     // 2048 x 512
    bf16* ffW2_t = Jw + 3506176;     //  512 x 2048

    const int M = Mrows;
    dim3 tw(32,8);

    // 0. weight transposes (f32 KxN -> bf16 NxK)
    wtrans<<<dim3(2048/32, 512/32), tw, 0, stream>>>(W_in,  Win_t,  512,  2048);
    wtrans<<<dim3(  64/32,1024/32), tw, 0, stream>>>(W_x,   Wx_t,   1024, 64);
    wtrans<<<dim3(1024/32,  32/32), tw, 0, stream>>>(W_dt,  Wdt_t,  32,   1024);
    wtrans<<<dim3( 512/32,1024/32), tw, 0, stream>>>(W_out, Wout_t, 1024, 512);
    wtrans<<<dim3(1024/32, 512/32), tw, 0, stream>>>(pw1_w, pw1_t,  512,  1024);
    wtrans<<<dim3( 512/32, 512/32), tw, 0, stream>>>(pw2_w, pw2_t,  512,  512);
    wtrans<<<dim3(2048/32, 512/32), tw, 0, stream>>>(ff_W1, ffW1_t, 512,  2048);
    wtrans<<<dim3( 512/32,2048/32), tw, 0, stream>>>(ff_W2, ffW2_t, 2048, 512);

    // 1. h = LN(x) -> bf16
    ln_kernel<false,true><<<M, 256, 0, stream>>>(x, ln_g, ln_b, nullptr, hb, Dc);
    // 2. xz = h @ W_in  (f32 out)
    mgemm<128,128,0,false,false,true,false><<<dim3(2048/128, M/128), 256, 0, stream>>>(
        hb, Dc, Win_t, nullptr, nullptr, xz_buf, nullptr, M, 2*DIc, Dc);
    // 3. xc = silu(causal dwconv(xi)) -> f32 + bf16
    causal_conv_silu<<<(M*DIc+255)/256, 256, 0, stream>>>(xz_buf, conv_w, conv_b, xc_buf, xcb);
    // 4. dbl = xc @ W_x  -> f32 + bf16
    mgemm<128,64,0,false,false,true,true><<<dim3(64/64, M/128), 256, 0, stream>>>(
        xcb, DIc, Wx_t, nullptr, nullptr, dbl_buf, dblb, M, 64, DIc);
    // 5. delta = softplus(dt @ W_dt + b_dt) -> f32
    mgemm<128,128,1,true,false,true,false><<<dim3(1024/128, M/128), 256, 0, stream>>>(
        dblb, 64, Wdt_t, b_dt, nullptr, dl_buf, nullptr, M, DIc, Rc);
    // 6. chunked selective scan -> y (bf16)
    scan_pass1<<<2048, 256, 0, stream>>>(dl_buf, xc_buf, dbl_buf, A_log, P_buf, H_buf);
    scan_combine<<<128, 256, 0, stream>>>(P_buf, H_buf, hs_buf);
    scan_pass3<<<2048, 256, 0, stream>>>(dl_buf, xc_buf, dbl_buf, xz_buf, A_log, Dp, hs_buf, yb);
    // 7. m = y @ W_out -> f32
    mgemm<128,128,0,false,false,true,false><<<dim3(512/128, M/128), 256, 0, stream>>>(
        yb, DIc, Wout_t, nullptr, nullptr, m_buf, nullptr, M, Dc, DIc);
    // 8. c = LN(m, cm) -> bf16
    ln_kernel<false,true><<<M, 256, 0, stream>>>(m_buf, cm_ln_g, cm_ln_b, nullptr, cb, Dc);
    // 9. c2 = c @ pw1 + b -> f32
    mgemm<128,128,0,true,false,true,false><<<dim3(1024/128, M/128), 256, 0, stream>>>(
        cb, Dc, pw1_t, pw1_b, nullptr, c2_buf, nullptr, M, 2*Dc, Dc);
    // 10. GLU -> f32
    glu_kernel<<<(M*Dc+255)/256, 256, 0, stream>>>(c2_buf, glu_buf);
    // 11. symmetric dwconv CK=31 + silu -> bf16
    sym_conv_silu<<<(M*Dc+255)/256, 256, 0, stream>>>(glu_buf, dw_w, dw_b, ccb);
    // 12. m = m + (cconv @ pw2 + b) -> f32 (in place)
    mgemm<128,128,0,true,true,true,false><<<dim3(512/128, M/128), 256, 0, stream>>>(
        ccb, Dc, pw2_t, pw2_b, m_buf, m_buf, nullptr, M, Dc, Dc);
    // 13. f = LN(m, ln) -> d_out (f32) + bf16
    ln_kernel<true,true><<<M, 256, 0, stream>>>(m_buf, ln_g, ln_b, f_buf, fb, Dc);
    // 14. g1 = gelu(f @ ff_W1 + b1) -> bf16
    mgemm<128,128,2,true,false,false,true><<<dim3(2048/128, M/128), 256, 0, stream>>>(
        fb, Dc, ffW1_t, ff_b1, nullptr, nullptr, g1b, M, DFFc, Dc);
    // 15. out = f + g1 @ ff_W2 + b2 -> d_out (in place: res tile == written tile)
    mgemm<128,128,0,true,true,true,false><<<dim3(512/128, M/128), 256, 0, stream>>>(
        g1b, DFFc, ffW2_t, ff_b2, f_buf, out, nullptr, M, Dc, DFFc);
}

// Round 4
// 594.837 us; speedup vs baseline: 5.2478x; 1.1629x over previous
//
#include <hip/hip_runtime.h>
#include <hip/hip_bf16.h>
#include <math.h>

// Problem constants
#define Bc   2
#define Lc   2048
#define Dc   512
#define DIc  1024
#define Nc   16
#define Kc   4
#define Rc   32
#define CKc  31
#define DFFc 2048
#define Mrows (Bc*Lc)   // 4096
#define CHUNK  32
#define NCHUNK 64

typedef __hip_bfloat16 bf16;
typedef short bf16x8 __attribute__((ext_vector_type(8)));
typedef float f32x4  __attribute__((ext_vector_type(4)));

__device__ __forceinline__ float sigmoidf_(float x){ return 1.f/(1.f+expf(-x)); }
__device__ __forceinline__ float siluf_(float x){ return x*sigmoidf_(x); }
__device__ __forceinline__ float softplusf_(float x){ return fmaxf(x,0.f)+log1pf(expf(-fabsf(x))); }
__device__ __forceinline__ float geluf_(float x){
    float x3 = x*x*x;
    return 0.5f*x*(1.f+tanhf(0.7978845608028654f*(x+0.044715f*x3)));
}

// ---------------- LayerNorm (one block per row, D=512); optional f32/bf16 outs ----------------
template<bool WF, bool WB>
__global__ void ln_kernel(const float* __restrict__ in, const float* __restrict__ g,
                          const float* __restrict__ bb, float* __restrict__ outf,
                          bf16* __restrict__ outb, int D) {
    int row = blockIdx.x;
    const float* x = in + (size_t)row * D;
    float s = 0.f, s2 = 0.f;
    for (int i = threadIdx.x; i < D; i += blockDim.x) { float v = x[i]; s += v; s2 += v*v; }
    #pragma unroll
    for (int off = 32; off; off >>= 1) { s += __shfl_down(s, off); s2 += __shfl_down(s2, off); }
    __shared__ float sh[2][4];
    int wave = threadIdx.x >> 6, lane = threadIdx.x & 63;
    if (lane == 0) { sh[0][wave] = s; sh[1][wave] = s2; }
    __syncthreads();
    if (threadIdx.x == 0) {
        float ts = 0.f, ts2 = 0.f;
        int nw = blockDim.x >> 6;
        for (int w = 0; w < nw; ++w) { ts += sh[0][w]; ts2 += sh[1][w]; }
        sh[0][0] = ts; sh[1][0] = ts2;
    }
    __syncthreads();
    float mean = sh[0][0] / D;
    float var  = sh[1][0] / D - mean*mean;
    float rstd = rsqrtf(var + 1e-5f);
    for (int i = threadIdx.x; i < D; i += blockDim.x) {
        float v = (x[i]-mean)*rstd*g[i] + bb[i];
        if (WF) outf[(size_t)row*D + i] = v;
        if (WB) outb[(size_t)row*D + i] = __float2bfloat16(v);
    }
}

// ---------------- weight transpose+cast: W (K x N, f32) -> Wt (N x K, bf16) ----------------
__global__ void wtrans(const float* __restrict__ W, bf16* __restrict__ Wt, int K, int N) {
    __shared__ float t[32][33];
    int bx = blockIdx.x, by = blockIdx.y;
    int tx = threadIdx.x, ty = threadIdx.y;   // 32 x 8
    #pragma unroll
    for (int i = 0; i < 32; i += 8)
        t[ty+i][tx] = W[(size_t)(by*32+ty+i)*N + bx*32+tx];
    __syncthreads();
    #pragma unroll
    for (int i = 0; i < 32; i += 8)
        Wt[(size_t)(bx*32+ty+i)*K + by*32+tx] = __float2bfloat16(t[tx][ty+i]);
}

// ---------------- bf16 MFMA GEMM: out = act(A@B + bias) (+res), B given as Wt = N x K ----------------
template<int BM, int BN, int ACT, bool BIAS, bool RES, bool WF32, bool WBF16>
__global__ __launch_bounds__(256) void mgemm(const bf16* __restrict__ A, int lda,
                                             const bf16* __restrict__ Wt,
                                             const float* __restrict__ bias,
                                             const float* __restrict__ res,
                                             float* __restrict__ outf,
                                             bf16* __restrict__ outb,
                                             int M, int N, int K) {
    constexpr int BK = 32;
    constexpr int WM = BM/2, WN = BN/2;       // per-wave tile
    constexpr int AM = WM/16, AN = WN/16;     // frags per wave
    constexpr int AITER = BM/64, BITER = BN/64;
    __shared__ __align__(16) bf16 As[BM*BK];
    __shared__ __align__(16) bf16 Bs[BN*BK];
    const int tid  = threadIdx.x;
    const int wave = tid >> 6, lane = tid & 63;
    const int r16  = lane & 15, kb = lane >> 4;
    const int bm = blockIdx.y*BM, bn = blockIdx.x*BN;
    const int wm = (wave>>1)*WM, wn = (wave&1)*WN;
    f32x4 acc[AM][AN] = {};

    for (int k0 = 0; k0 < K; k0 += BK) {
        uint4 ar[AITER], br[BITER];
        #pragma unroll
        for (int it = 0; it < AITER; ++it) {
            int c = it*256 + tid;
            ar[it] = *(const uint4*)(&A[(size_t)(bm + (c>>2))*lda + k0 + (c&3)*8]);
        }
        #pragma unroll
        for (int it = 0; it < BITER; ++it) {
            int c = it*256 + tid;
            br[it] = *(const uint4*)(&Wt[(size_t)(bn + (c>>2))*K + k0 + (c&3)*8]);
        }
        __syncthreads();   // previous iteration's reads done before overwrite
        #pragma unroll
        for (int it = 0; it < AITER; ++it)
            *(uint4*)(&As[(size_t)(it*256 + tid)*8]) = ar[it];
        #pragma unroll
        for (int it = 0; it < BITER; ++it)
            *(uint4*)(&Bs[(size_t)(it*256 + tid)*8]) = br[it];
        __syncthreads();
        bf16x8 af[AM], bfr[AN];
        #pragma unroll
        for (int mi = 0; mi < AM; ++mi)
            af[mi] = *(const bf16x8*)(&As[(wm + mi*16 + r16)*BK + kb*8]);
        #pragma unroll
        for (int ni = 0; ni < AN; ++ni)
            bfr[ni] = *(const bf16x8*)(&Bs[(wn + ni*16 + r16)*BK + kb*8]);
        #pragma unroll
        for (int mi = 0; mi < AM; ++mi)
            #pragma unroll
            for (int ni = 0; ni < AN; ++ni)
                acc[mi][ni] = __builtin_amdgcn_mfma_f32_16x16x32_bf16(af[mi], bfr[ni], acc[mi][ni], 0, 0, 0);
    }

    // epilogue: C/D map col=lane&15, row=(lane>>4)*4+r
    #pragma unroll
    for (int mi = 0; mi < AM; ++mi) {
        #pragma unroll
        for (int ni = 0; ni < AN; ++ni) {
            #pragma unroll
            for (int r = 0; r < 4; ++r) {
                int grow = bm + wm + mi*16 + kb*4 + r;
                int gcol = bn + wn + ni*16 + r16;
                float v = acc[mi][ni][r];
                if (BIAS) v += bias[gcol];
                if (ACT == 1) v = softplusf_(v);
                else if (ACT == 2) v = geluf_(v);
                if (RES) v += res[(size_t)grow*N + gcol];
                if (WF32)  outf[(size_t)grow*N + gcol] = v;
                if (WBF16) outb[(size_t)grow*N + gcol] = __float2bfloat16(v);
            }
        }
    }
}

// ---------------- causal depthwise conv K=4 + silu; xi separate (stride DIc) ----------------
__global__ void causal_conv_silu(const float* __restrict__ xi, const float* __restrict__ w,
                                 const float* __restrict__ bias, float* __restrict__ xc,
                                 bf16* __restrict__ xcb) {
    int idx = blockIdx.x*blockDim.x + threadIdx.x;
    if (idx >= Bc*Lc*DIc) return;
    int d  = idx & (DIc-1);
    int bl = idx >> 10;          // b*L + l
    int l  = bl & (Lc-1);
    float acc = bias[d];
    #pragma unroll
    for (int k = 0; k < Kc; ++k) {
        int ls = l - (Kc-1) + k;
        if (ls >= 0) acc = fmaf(xi[((size_t)(bl - (Kc-1) + k))*DIc + d], w[d*Kc + k], acc);
    }
    float v = siluf_(acc);
    xc[idx] = v;
    xcb[idx] = __float2bfloat16(v);
}

// ---------------- chunked selective scan, thread-per-channel, 16 states in registers ----------------
// blockIdx.x = bc*4 + dgroup; bc = b + 2*chunk. Block covers 256 consecutive d at one (b,chunk):
// rowi is block-uniform -> B/C row loads are broadcast; delta/xc/z loads coalesced across lanes.
__global__ __launch_bounds__(256) void scan_pass1(const float* __restrict__ delta, const float* __restrict__ xc,
                                                  const float* __restrict__ dbl, const float* __restrict__ A_log,
                                                  float* __restrict__ P, float* __restrict__ H) {
    int dgroup = blockIdx.x & 3;
    int bc = blockIdx.x >> 2;           // 0..127
    int b = bc & 1, chunk = bc >> 1;    // chunk 0..63
    int d = dgroup*256 + threadIdx.x;
    float Av[16];
    #pragma unroll
    for (int j = 0; j < 4; ++j) {
        f32x4 v = *(const f32x4*)(&A_log[d*16 + 4*j]);
        #pragma unroll
        for (int q = 0; q < 4; ++q) Av[4*j+q] = -__expf(v[q]);
    }
    float h[16], Pl[16];
    #pragma unroll
    for (int n = 0; n < 16; ++n) { h[n] = 0.f; Pl[n] = 1.f; }
    size_t row0 = (size_t)b*Lc + (size_t)chunk*CHUNK;
    for (int i = 0; i < CHUNK; ++i) {
        size_t rowi = row0 + i;
        float dv  = delta[rowi*DIc + d];
        float xcv = xc[rowi*DIc + d];
        float dxc = dv*xcv;
        f32x4 B0 = *(const f32x4*)(&dbl[rowi*64 + Rc + 0]);
        f32x4 B1 = *(const f32x4*)(&dbl[rowi*64 + Rc + 4]);
        f32x4 B2 = *(const f32x4*)(&dbl[rowi*64 + Rc + 8]);
        f32x4 B3 = *(const f32x4*)(&dbl[rowi*64 + Rc + 12]);
        float Bv[16];
        #pragma unroll
        for (int q = 0; q < 4; ++q) { Bv[q]=B0[q]; Bv[4+q]=B1[q]; Bv[8+q]=B2[q]; Bv[12+q]=B3[q]; }
        #pragma unroll
        for (int n = 0; n < 16; ++n) {
            float a = __expf(dv*Av[n]);
            h[n] = fmaf(a, h[n], dxc*Bv[n]);
            Pl[n] *= a;
        }
    }
    size_t pidx = ((size_t)chunk*2048 + (size_t)b*DIc + d) * 16;
    #pragma unroll
    for (int j = 0; j < 4; ++j) {
        f32x4 vp, vh;
        #pragma unroll
        for (int q = 0; q < 4; ++q) { vp[q] = Pl[4*j+q]; vh[q] = h[4*j+q]; }
        *(f32x4*)(&P[pidx + 4*j]) = vp;
        *(f32x4*)(&H[pidx + 4*j]) = vh;
    }
}

// Serial combine across chunks; writes prefix state (hstart) back into P in place.
__global__ void scan_combine(float* __restrict__ P, const float* __restrict__ H) {
    int t = blockIdx.x*blockDim.x + threadIdx.x;  // 0..32767 = (b*DI+d)*16+n
    float h = 0.f;
    #pragma unroll
    for (int c = 0; c < NCHUNK; ++c) {
        size_t idx = (size_t)c*32768 + t;
        float Pv = P[idx], Hv = H[idx];
        P[idx] = h;                 // hstart for chunk c
        h = fmaf(Pv, h, Hv);
    }
}

__global__ __launch_bounds__(256) void scan_pass3(const float* __restrict__ delta, const float* __restrict__ xc,
                                                  const float* __restrict__ dbl, const float* __restrict__ z,
                                                  const float* __restrict__ A_log, const float* __restrict__ Dp,
                                                  const float* __restrict__ hstart, bf16* __restrict__ y) {
    int dgroup = blockIdx.x & 3;
    int bc = blockIdx.x >> 2;
    int b = bc & 1, chunk = bc >> 1;
    int d = dgroup*256 + threadIdx.x;
    float Av[16];
    #pragma unroll
    for (int j = 0; j < 4; ++j) {
        f32x4 v = *(const f32x4*)(&A_log[d*16 + 4*j]);
        #pragma unroll
        for (int q = 0; q < 4; ++q) Av[4*j+q] = -__expf(v[q]);
    }
    float Dv = Dp[d];
    float h[16];
    size_t pidx = ((size_t)chunk*2048 + (size_t)b*DIc + d) * 16;
    #pragma unroll
    for (int j = 0; j < 4; ++j) {
        f32x4 v = *(const f32x4*)(&hstart[pidx + 4*j]);
        #pragma unroll
        for (int q = 0; q < 4; ++q) h[4*j+q] = v[q];
    }
    size_t row0 = (size_t)b*Lc + (size_t)chunk*CHUNK;
    for (int i = 0; i < CHUNK; ++i) {
        size_t rowi = row0 + i;
        float dv  = delta[rowi*DIc + d];
        float xcv = xc[rowi*DIc + d];
        float dxc = dv*xcv;
        f32x4 B0 = *(const f32x4*)(&dbl[rowi*64 + Rc + 0]);
        f32x4 B1 = *(const f32x4*)(&dbl[rowi*64 + Rc + 4]);
        f32x4 B2 = *(const f32x4*)(&dbl[rowi*64 + Rc + 8]);
        f32x4 B3 = *(const f32x4*)(&dbl[rowi*64 + Rc + 12]);
        f32x4 C0 = *(const f32x4*)(&dbl[rowi*64 + Rc + Nc + 0]);
        f32x4 C1 = *(const f32x4*)(&dbl[rowi*64 + Rc + Nc + 4]);
        f32x4 C2 = *(const f32x4*)(&dbl[rowi*64 + Rc + Nc + 8]);
        f32x4 C3 = *(const f32x4*)(&dbl[rowi*64 + Rc + Nc + 12]);
        float Bv[16], Cv[16];
        #pragma unroll
        for (int q = 0; q < 4; ++q) {
            Bv[q]=B0[q]; Bv[4+q]=B1[q]; Bv[8+q]=B2[q]; Bv[12+q]=B3[q];
            Cv[q]=C0[q]; Cv[4+q]=C1[q]; Cv[8+q]=C2[q]; Cv[12+q]=C3[q];
        }
        float s0=0.f, s1=0.f, s2=0.f, s3=0.f;
        #pragma unroll
        for (int n = 0; n < 16; ++n) {
            float a = __expf(dv*Av[n]);
            h[n] = fmaf(a, h[n], dxc*Bv[n]);
        }
        #pragma unroll
        for (int j = 0; j < 4; ++j) {
            s0 = fmaf(h[4*j+0], Cv[4*j+0], s0);
            s1 = fmaf(h[4*j+1], Cv[4*j+1], s1);
            s2 = fmaf(h[4*j+2], Cv[4*j+2], s2);
            s3 = fmaf(h[4*j+3], Cv[4*j+3], s3);
        }
        float contrib = (s0+s1)+(s2+s3);
        float zv = z[rowi*DIc + d];
        y[rowi*DIc + d] = __float2bfloat16((contrib + Dv*xcv) * siluf_(zv));
    }
}

// ---------------- GLU ----------------
__global__ void glu_kernel(const float* __restrict__ c2, float* __restrict__ out) {
    int idx = blockIdx.x*blockDim.x + threadIdx.x;
    if (idx >= Bc*Lc*Dc) return;
    int col = idx & (Dc-1); int row = idx >> 9;
    float a  = c2[(size_t)row*(2*Dc) + col];
    float gg = c2[(size_t)row*(2*Dc) + Dc + col];
    out[idx] = a * sigmoidf_(gg);
}

// ---------------- symmetric depthwise conv CK=31 + silu -> bf16 ----------------
__global__ void sym_conv_silu(const float* __restrict__ in, const float* __restrict__ w,
                              const float* __restrict__ bias, bf16* __restrict__ out) {
    int idx = blockIdx.x*blockDim.x + threadIdx.x;
    if (idx >= Bc*Lc*Dc) return;
    int d  = idx & (Dc-1);
    int bl = idx >> 9;
    int l  = bl & (Lc-1);
    float acc = bias[d];
    #pragma unroll
    for (int k = 0; k < CKc; ++k) {
        int ls = l - (CKc-1)/2 + k;
        if (ls >= 0 && ls < Lc)
            acc = fmaf(in[((size_t)(bl + ls - l))*Dc + d], w[d*CKc + k], acc);
    }
    out[idx] = __float2bfloat16(siluf_(acc));
}

extern "C" void kernel_launch(void* const* d_in, const int* in_sizes, int n_in,
                              void* d_out, int out_size, void* d_ws, size_t ws_size,
                              hipStream_t stream) {
    const float* x      = (const float*)d_in[0];
    const float* ln_g   = (const float*)d_in[1];
    const float* ln_b   = (const float*)d_in[2];
    const float* W_in   = (const float*)d_in[3];
    const float* conv_w = (const float*)d_in[4];
    const float* conv_b = (const float*)d_in[5];
    const float* W_x    = (const float*)d_in[6];
    const float* W_dt   = (const float*)d_in[7];
    const float* b_dt   = (const float*)d_in[8];
    const float* A_log  = (const float*)d_in[9];
    const float* Dp     = (const float*)d_in[10];
    const float* W_out  = (const float*)d_in[11];
    const float* cm_ln_g= (const float*)d_in[12];
    const float* cm_ln_b= (const float*)d_in[13];
    const float* pw1_w  = (const float*)d_in[14];
    const float* pw1_b  = (const float*)d_in[15];
    const float* dw_w   = (const float*)d_in[16];
    const float* dw_b   = (const float*)d_in[17];
    const float* pw2_w  = (const float*)d_in[18];
    const float* pw2_b  = (const float*)d_in[19];
    const float* ff_W1  = (const float*)d_in[20];
    const float* ff_b1  = (const float*)d_in[21];
    const float* ff_W2  = (const float*)d_in[22];
    const float* ff_b2  = (const float*)d_in[23];
    float* out = (float*)d_out;
    float* ws  = (float*)d_ws;

    // ---- workspace layout (float offsets), total 22,986,752 floats ~92 MB ----
    float* A_  = ws;                 // 4,194,304: xi f32 -> P(2M)+H(2M) -> c2 (4M)
    float* A2_ = ws + 4194304;       // 4,194,304: z f32 -> glu (2M)
    float* B_  = ws + 8388608;       // 4,194,304: xc f32 -> g1_bf16
    float* C_  = ws + 12582912;      //   262,144: dbl f32
    float* D_  = ws + 12845056;      // 4,194,304: delta -> m (2M)
    float* F_  = ws + 17039360;      // 1,572,864: dbl_bf16 / c_bf16 / cc_bf16 / f_bf16
    float* H_  = ws + 18612224;      // 2,097,152: h_bf16 / xc_bf16 / y_bf16
    float* J_  = ws + 20709376;      // 2,277,376: transposed bf16 weights

    float* xi_buf  = A_;
    float* P_buf   = A_;             // 64*32768 = 2,097,152
    float* H_buf   = A_ + 2097152;
    float* c2_buf  = A_;
    float* z_buf   = A2_;
    float* glu_buf = A2_;
    float* xc_buf  = B_;
    bf16*  g1b     = (bf16*)B_;
    float* dbl_buf = C_;
    float* dl_buf  = D_;
    float* m_buf   = D_;
    bf16*  dblb    = (bf16*)F_;
    bf16*  cb      = (bf16*)F_;
    bf16*  ccb     = (bf16*)F_;
    bf16*  fb      = (bf16*)F_;
    bf16*  hb      = (bf16*)H_;
    bf16*  xcb     = (bf16*)H_;
    bf16*  yb      = (bf16*)H_;
    float* f_buf   = out;            // f lives in d_out; GEMM15 reads it as residual

    bf16* Jw = (bf16*)J_;
    bf16* Win_t  = Jw;               // 2048 x 512
    bf16* Wx_t   = Jw + 1048576;     //   64 x 1024
    bf16* Wdt_t  = Jw + 1114112;     // 1024 x 32
    bf16* Wout_t = Jw + 1146880;     //  512 x 1024
    bf16* pw1_t  = Jw + 1671168;     // 1024 x 512
    bf16* pw2_t  = Jw + 2195456;     //  512 x 512
    bf16* ffW1_t = Jw + 2457600;     // 2048 x 512
    bf16* ffW2_t = Jw + 3506176;     //  512 x 2048

    const int M = Mrows;
    dim3 tw(32,8);

    // 0. weight transposes (f32 KxN -> bf16 NxK)
    wtrans<<<dim3(2048/32, 512/32), tw, 0, stream>>>(W_in,  Win_t,  512,  2048);
    wtrans<<<dim3(  64/32,1024/32), tw, 0, stream>>>(W_x,   Wx_t,   1024, 64);
    wtrans<<<dim3(1024/32,  32/32), tw, 0, stream>>>(W_dt,  Wdt_t,  32,   1024);
    wtrans<<<dim3( 512/32,1024/32), tw, 0, stream>>>(W_out, Wout_t, 1024, 512);
    wtrans<<<dim3(1024/32, 512/32), tw, 0, stream>>>(pw1_w, pw1_t,  512,  1024);
    wtrans<<<dim3( 512/32, 512/32), tw, 0, stream>>>(pw2_w, pw2_t,  512,  512);
    wtrans<<<dim3(2048/32, 512/32), tw, 0, stream>>>(ff_W1, ffW1_t, 512,  2048);
    wtrans<<<dim3( 512/32,2048/32), tw, 0, stream>>>(ff_W2, ffW2_t, 2048, 512);

    // 1. h = LN(x) -> bf16
    ln_kernel<false,true><<<M, 256, 0, stream>>>(x, ln_g, ln_b, nullptr, hb, Dc);
    // 2a. xi = h @ W_in[:, :DI]   2b. z = h @ W_in[:, DI:]
    mgemm<128,128,0,false,false,true,false><<<dim3(1024/128, M/128), 256, 0, stream>>>(
        hb, Dc, Win_t, nullptr, nullptr, xi_buf, nullptr, M, DIc, Dc);
    mgemm<128,128,0,false,false,true,false><<<dim3(1024/128, M/128), 256, 0, stream>>>(
        hb, Dc, Win_t + (size_t)DIc*Dc, nullptr, nullptr, z_buf, nullptr, M, DIc, Dc);
    // 3. xc = silu(causal dwconv(xi)) -> f32 + bf16
    causal_conv_silu<<<(M*DIc+255)/256, 256, 0, stream>>>(xi_buf, conv_w, conv_b, xc_buf, xcb);
    // 4. dbl = xc @ W_x  -> f32 + bf16
    mgemm<128,64,0,false,false,true,true><<<dim3(64/64, M/128), 256, 0, stream>>>(
        xcb, DIc, Wx_t, nullptr, nullptr, dbl_buf, dblb, M, 64, DIc);
    // 5. delta = softplus(dt @ W_dt + b_dt) -> f32
    mgemm<128,128,1,true,false,true,false><<<dim3(1024/128, M/128), 256, 0, stream>>>(
        dblb, 64, Wdt_t, b_dt, nullptr, dl_buf, nullptr, M, DIc, Rc);
    // 6. chunked selective scan -> y (bf16)
    scan_pass1<<<512, 256, 0, stream>>>(dl_buf, xc_buf, dbl_buf, A_log, P_buf, H_buf);
    scan_combine<<<128, 256, 0, stream>>>(P_buf, H_buf);
    scan_pass3<<<512, 256, 0, stream>>>(dl_buf, xc_buf, dbl_buf, z_buf, A_log, Dp, P_buf, yb);
    // 7. m = y @ W_out -> f32
    mgemm<128,128,0,false,false,true,false><<<dim3(512/128, M/128), 256, 0, stream>>>(
        yb, DIc, Wout_t, nullptr, nullptr, m_buf, nullptr, M, Dc, DIc);
    // 8. c = LN(m, cm) -> bf16
    ln_kernel<false,true><<<M, 256, 0, stream>>>(m_buf, cm_ln_g, cm_ln_b, nullptr, cb, Dc);
    // 9. c2 = c @ pw1 + b -> f32
    mgemm<128,128,0,true,false,true,false><<<dim3(1024/128, M/128), 256, 0, stream>>>(
        cb, Dc, pw1_t, pw1_b, nullptr, c2_buf, nullptr, M, 2*Dc, Dc);
    // 10. GLU -> f32
    glu_kernel<<<(M*Dc+255)/256, 256, 0, stream>>>(c2_buf, glu_buf);
    // 11. symmetric dwconv CK=31 + silu -> bf16
    sym_conv_silu<<<(M*Dc+255)/256, 256, 0, stream>>>(glu_buf, dw_w, dw_b, ccb);
    // 12. m = m + (cconv @ pw2 + b) -> f32 (in place)
    mgemm<128,128,0,true,true,true,false><<<dim3(512/128, M/128), 256, 0, stream>>>(
        ccb, Dc, pw2_t, pw2_b, m_buf, m_buf, nullptr, M, Dc, Dc);
    // 13. f = LN(m, ln) -> d_out (f32) + bf16
    ln_kernel<true,true><<<M, 256, 0, stream>>>(m_buf, ln_g, ln_b, f_buf, fb, Dc);
    // 14. g1 = gelu(f @ ff_W1 + b1) -> bf16
    mgemm<128,128,2,true,false,false,true><<<dim3(2048/128, M/128), 256, 0, stream>>>(
        fb, Dc, ffW1_t, ff_b1, nullptr, nullptr, g1b, M, DFFc, Dc);
    // 15. out = f + g1 @ ff_W2 + b2 -> d_out (in place: res tile == written tile)
    mgemm<128,128,0,true,true,true,false><<<dim3(512/128, M/128), 256, 0, stream>>>(
        g1b, DFFc, ffW2_t, ff_b2, f_buf, out, nullptr, M, Dc, DFFc);
}

// Round 5
// 399.137 us; speedup vs baseline: 7.8208x; 1.4903x over previous
//
#include <hip/hip_runtime.h>
#include <hip/hip_bf16.h>
#include <math.h>

// Problem constants
#define Bc   2
#define Lc   2048
#define Dc   512
#define DIc  1024
#define Nc   16
#define Kc   4
#define Rc   32
#define CKc  31
#define DFFc 2048
#define Mrows (Bc*Lc)   // 4096
#define CHUNK  32
#define NCHUNK 64

typedef __hip_bfloat16 bf16;
typedef short bf16x8 __attribute__((ext_vector_type(8)));
typedef float f32x4  __attribute__((ext_vector_type(4)));

__device__ __forceinline__ float sigmoidf_(float x){ return 1.f/(1.f+expf(-x)); }
__device__ __forceinline__ float siluf_(float x){ return x*sigmoidf_(x); }
__device__ __forceinline__ float softplusf_(float x){ return fmaxf(x,0.f)+log1pf(expf(-fabsf(x))); }
__device__ __forceinline__ float geluf_(float x){
    float x3 = x*x*x;
    return 0.5f*x*(1.f+tanhf(0.7978845608028654f*(x+0.044715f*x3)));
}

// async global -> LDS, 16 bytes/lane; lptr is wave-uniform base (HW adds lane*16)
__device__ __forceinline__ void gload16(const void* g, void* l) {
    __builtin_amdgcn_global_load_lds((const __attribute__((address_space(1))) void*)g,
                                     (__attribute__((address_space(3))) void*)l, 16, 0, 0);
}

// ---------------- LayerNorm (one block per row, D=512); optional f32/bf16 outs ----------------
template<bool WF, bool WB>
__global__ void ln_kernel(const float* __restrict__ in, const float* __restrict__ g,
                          const float* __restrict__ bb, float* __restrict__ outf,
                          bf16* __restrict__ outb, int D) {
    int row = blockIdx.x;
    const float* x = in + (size_t)row * D;
    float s = 0.f, s2 = 0.f;
    for (int i = threadIdx.x; i < D; i += blockDim.x) { float v = x[i]; s += v; s2 += v*v; }
    #pragma unroll
    for (int off = 32; off; off >>= 1) { s += __shfl_down(s, off); s2 += __shfl_down(s2, off); }
    __shared__ float sh[2][4];
    int wave = threadIdx.x >> 6, lane = threadIdx.x & 63;
    if (lane == 0) { sh[0][wave] = s; sh[1][wave] = s2; }
    __syncthreads();
    if (threadIdx.x == 0) {
        float ts = 0.f, ts2 = 0.f;
        int nw = blockDim.x >> 6;
        for (int w = 0; w < nw; ++w) { ts += sh[0][w]; ts2 += sh[1][w]; }
        sh[0][0] = ts; sh[1][0] = ts2;
    }
    __syncthreads();
    float mean = sh[0][0] / D;
    float var  = sh[1][0] / D - mean*mean;
    float rstd = rsqrtf(var + 1e-5f);
    for (int i = threadIdx.x; i < D; i += blockDim.x) {
        float v = (x[i]-mean)*rstd*g[i] + bb[i];
        if (WF) outf[(size_t)row*D + i] = v;
        if (WB) outb[(size_t)row*D + i] = __float2bfloat16(v);
    }
}

// ---------------- weight transpose+cast: W (K x N, f32) -> Wt (N x K, bf16) ----------------
__global__ void wtrans(const float* __restrict__ W, bf16* __restrict__ Wt, int K, int N) {
    __shared__ float t[32][33];
    int bx = blockIdx.x, by = blockIdx.y;
    int tx = threadIdx.x, ty = threadIdx.y;   // 32 x 8
    #pragma unroll
    for (int i = 0; i < 32; i += 8)
        t[ty+i][tx] = W[(size_t)(by*32+ty+i)*N + bx*32+tx];
    __syncthreads();
    #pragma unroll
    for (int i = 0; i < 32; i += 8)
        Wt[(size_t)(bx*32+ty+i)*K + by*32+tx] = __float2bfloat16(t[tx][ty+i]);
}

// ---------------- bf16 MFMA GEMM, 2-phase dbuf + global_load_lds + XOR swizzle ----------------
// A: M x K bf16 (row stride lda), Wt: N x K bf16. out = act(A@Wt^T + bias) (+res).
// LDS linear dest for DMA; global source pre-permuted chunk^=(row&3); ds_read applies same XOR.
template<int BM, int BN, int ACT, bool BIAS, bool RES, bool WF32, bool WBF16>
__global__ __launch_bounds__(256) void mgemm(const bf16* __restrict__ A, int lda,
                                             const bf16* __restrict__ Wt,
                                             const float* __restrict__ bias,
                                             const float* __restrict__ res,
                                             float* __restrict__ outf,
                                             bf16* __restrict__ outb,
                                             int M, int N, int K) {
    constexpr int BK = 32;
    constexpr int WM = BM/2, WN = BN/2;       // per-wave tile
    constexpr int AM = WM/16, AN = WN/16;     // frags per wave
    constexpr int AISS = BM/64, BISS = BN/64; // 1KB staging issues per wave
    __shared__ __align__(16) bf16 As[2][BM*BK];
    __shared__ __align__(16) bf16 Bs[2][BN*BK];
    const int tid  = threadIdx.x;
    const int wave = tid >> 6, lane = tid & 63;
    const int r16  = lane & 15, kb = lane >> 4;
    // bijective XCD swizzle on flattened block id (nwg % 8 == 0 for all launches here)
    const int gx = gridDim.x;
    const int nwg = gx*gridDim.y;
    const int id  = blockIdx.y*gx + blockIdx.x;
    const int sid = (id & 7)*(nwg >> 3) + (id >> 3);
    const int bm = (sid / gx)*BM, bn = (sid % gx)*BN;
    const int wm = (wave>>1)*WM, wn = (wave&1)*WN;
    f32x4 acc[AM][AN] = {};
    const int nt = K / BK;

    // stage tile kt into buffer buf (async)
    auto stage = [&](int buf, int kt) {
        #pragma unroll
        for (int it = 0; it < AISS; ++it) {
            int base = (wave*AISS + it) << 10;          // wave-uniform byte base
            int Lb   = base + (lane << 4);              // this lane's dest byte
            int row  = Lb >> 6;
            int gch  = ((Lb >> 4) & 3) ^ (row & 3);     // inverse swizzle on source
            gload16(A + (size_t)(bm + row)*lda + kt*BK + gch*8, (char*)As[buf] + base);
        }
        #pragma unroll
        for (int it = 0; it < BISS; ++it) {
            int base = (wave*BISS + it) << 10;
            int Lb   = base + (lane << 4);
            int row  = Lb >> 6;
            int gch  = ((Lb >> 4) & 3) ^ (row & 3);
            gload16(Wt + (size_t)(bn + row)*K + kt*BK + gch*8, (char*)Bs[buf] + base);
        }
    };

    stage(0, 0);
    __syncthreads();
    for (int t = 0; t < nt; ++t) {
        int cur = t & 1;
        if (t + 1 < nt) stage(cur ^ 1, t + 1);
        bf16x8 af[AM], bfr[AN];
        #pragma unroll
        for (int mi = 0; mi < AM; ++mi) {
            int r = wm + mi*16 + r16;
            af[mi] = *(const bf16x8*)((const char*)As[cur] + r*64 + ((kb ^ (r & 3)) << 4));
        }
        #pragma unroll
        for (int ni = 0; ni < AN; ++ni) {
            int r = wn + ni*16 + r16;
            bfr[ni] = *(const bf16x8*)((const char*)Bs[cur] + r*64 + ((kb ^ (r & 3)) << 4));
        }
        #pragma unroll
        for (int mi = 0; mi < AM; ++mi)
            #pragma unroll
            for (int ni = 0; ni < AN; ++ni)
                acc[mi][ni] = __builtin_amdgcn_mfma_f32_16x16x32_bf16(af[mi], bfr[ni], acc[mi][ni], 0, 0, 0);
        __syncthreads();   // drains stage(t+1) DMA + all waves done reading buf[cur]
    }

    // epilogue: C/D map col=lane&15, row=(lane>>4)*4+r
    #pragma unroll
    for (int mi = 0; mi < AM; ++mi) {
        #pragma unroll
        for (int ni = 0; ni < AN; ++ni) {
            #pragma unroll
            for (int r = 0; r < 4; ++r) {
                int grow = bm + wm + mi*16 + kb*4 + r;
                int gcol = bn + wn + ni*16 + r16;
                float v = acc[mi][ni][r];
                if (BIAS) v += bias[gcol];
                if (ACT == 1) v = softplusf_(v);
                else if (ACT == 2) v = geluf_(v);
                if (RES) v += res[(size_t)grow*N + gcol];
                if (WF32)  outf[(size_t)grow*N + gcol] = v;
                if (WBF16) outb[(size_t)grow*N + gcol] = __float2bfloat16(v);
            }
        }
    }
}

// ---------------- causal depthwise conv K=4 + silu; xi separate (stride DIc) ----------------
__global__ void causal_conv_silu(const float* __restrict__ xi, const float* __restrict__ w,
                                 const float* __restrict__ bias, float* __restrict__ xc,
                                 bf16* __restrict__ xcb) {
    int idx = blockIdx.x*blockDim.x + threadIdx.x;
    if (idx >= Bc*Lc*DIc) return;
    int d  = idx & (DIc-1);
    int bl = idx >> 10;          // b*L + l
    int l  = bl & (Lc-1);
    float acc = bias[d];
    #pragma unroll
    for (int k = 0; k < Kc; ++k) {
        int ls = l - (Kc-1) + k;
        if (ls >= 0) acc = fmaf(xi[((size_t)(bl - (Kc-1) + k))*DIc + d], w[d*Kc + k], acc);
    }
    float v = siluf_(acc);
    xc[idx] = v;
    xcb[idx] = __float2bfloat16(v);
}

// ---------------- chunked selective scan, thread-per-channel, 16 states in registers ----------------
__global__ __launch_bounds__(256) void scan_pass1(const float* __restrict__ delta, const float* __restrict__ xc,
                                                  const float* __restrict__ dbl, const float* __restrict__ A_log,
                                                  float* __restrict__ P, float* __restrict__ H) {
    int dgroup = blockIdx.x & 3;
    int bc = blockIdx.x >> 2;           // 0..127
    int b = bc & 1, chunk = bc >> 1;    // chunk 0..63
    int d = dgroup*256 + threadIdx.x;
    float Av[16];
    #pragma unroll
    for (int j = 0; j < 4; ++j) {
        f32x4 v = *(const f32x4*)(&A_log[d*16 + 4*j]);
        #pragma unroll
        for (int q = 0; q < 4; ++q) Av[4*j+q] = -__expf(v[q]);
    }
    float h[16], Pl[16];
    #pragma unroll
    for (int n = 0; n < 16; ++n) { h[n] = 0.f; Pl[n] = 1.f; }
    size_t row0 = (size_t)b*Lc + (size_t)chunk*CHUNK;
    for (int i = 0; i < CHUNK; ++i) {
        size_t rowi = row0 + i;
        float dv  = delta[rowi*DIc + d];
        float xcv = xc[rowi*DIc + d];
        float dxc = dv*xcv;
        f32x4 B0 = *(const f32x4*)(&dbl[rowi*64 + Rc + 0]);
        f32x4 B1 = *(const f32x4*)(&dbl[rowi*64 + Rc + 4]);
        f32x4 B2 = *(const f32x4*)(&dbl[rowi*64 + Rc + 8]);
        f32x4 B3 = *(const f32x4*)(&dbl[rowi*64 + Rc + 12]);
        float Bv[16];
        #pragma unroll
        for (int q = 0; q < 4; ++q) { Bv[q]=B0[q]; Bv[4+q]=B1[q]; Bv[8+q]=B2[q]; Bv[12+q]=B3[q]; }
        #pragma unroll
        for (int n = 0; n < 16; ++n) {
            float a = __expf(dv*Av[n]);
            h[n] = fmaf(a, h[n], dxc*Bv[n]);
            Pl[n] *= a;
        }
    }
    size_t pidx = ((size_t)chunk*2048 + (size_t)b*DIc + d) * 16;
    #pragma unroll
    for (int j = 0; j < 4; ++j) {
        f32x4 vp, vh;
        #pragma unroll
        for (int q = 0; q < 4; ++q) { vp[q] = Pl[4*j+q]; vh[q] = h[4*j+q]; }
        *(f32x4*)(&P[pidx + 4*j]) = vp;
        *(f32x4*)(&H[pidx + 4*j]) = vh;
    }
}

// Serial combine across chunks; writes prefix state (hstart) back into P in place.
__global__ void scan_combine(float* __restrict__ P, const float* __restrict__ H) {
    int t = blockIdx.x*blockDim.x + threadIdx.x;  // 0..32767 = (b*DI+d)*16+n
    float h = 0.f;
    #pragma unroll
    for (int c = 0; c < NCHUNK; ++c) {
        size_t idx = (size_t)c*32768 + t;
        float Pv = P[idx], Hv = H[idx];
        P[idx] = h;                 // hstart for chunk c
        h = fmaf(Pv, h, Hv);
    }
}

__global__ __launch_bounds__(256) void scan_pass3(const float* __restrict__ delta, const float* __restrict__ xc,
                                                  const float* __restrict__ dbl, const float* __restrict__ z,
                                                  const float* __restrict__ A_log, const float* __restrict__ Dp,
                                                  const float* __restrict__ hstart, bf16* __restrict__ y) {
    int dgroup = blockIdx.x & 3;
    int bc = blockIdx.x >> 2;
    int b = bc & 1, chunk = bc >> 1;
    int d = dgroup*256 + threadIdx.x;
    float Av[16];
    #pragma unroll
    for (int j = 0; j < 4; ++j) {
        f32x4 v = *(const f32x4*)(&A_log[d*16 + 4*j]);
        #pragma unroll
        for (int q = 0; q < 4; ++q) Av[4*j+q] = -__expf(v[q]);
    }
    float Dv = Dp[d];
    float h[16];
    size_t pidx = ((size_t)chunk*2048 + (size_t)b*DIc + d) * 16;
    #pragma unroll
    for (int j = 0; j < 4; ++j) {
        f32x4 v = *(const f32x4*)(&hstart[pidx + 4*j]);
        #pragma unroll
        for (int q = 0; q < 4; ++q) h[4*j+q] = v[q];
    }
    size_t row0 = (size_t)b*Lc + (size_t)chunk*CHUNK;
    for (int i = 0; i < CHUNK; ++i) {
        size_t rowi = row0 + i;
        float dv  = delta[rowi*DIc + d];
        float xcv = xc[rowi*DIc + d];
        float dxc = dv*xcv;
        f32x4 B0 = *(const f32x4*)(&dbl[rowi*64 + Rc + 0]);
        f32x4 B1 = *(const f32x4*)(&dbl[rowi*64 + Rc + 4]);
        f32x4 B2 = *(const f32x4*)(&dbl[rowi*64 + Rc + 8]);
        f32x4 B3 = *(const f32x4*)(&dbl[rowi*64 + Rc + 12]);
        f32x4 C0 = *(const f32x4*)(&dbl[rowi*64 + Rc + Nc + 0]);
        f32x4 C1 = *(const f32x4*)(&dbl[rowi*64 + Rc + Nc + 4]);
        f32x4 C2 = *(const f32x4*)(&dbl[rowi*64 + Rc + Nc + 8]);
        f32x4 C3 = *(const f32x4*)(&dbl[rowi*64 + Rc + Nc + 12]);
        float Bv[16], Cv[16];
        #pragma unroll
        for (int q = 0; q < 4; ++q) {
            Bv[q]=B0[q]; Bv[4+q]=B1[q]; Bv[8+q]=B2[q]; Bv[12+q]=B3[q];
            Cv[q]=C0[q]; Cv[4+q]=C1[q]; Cv[8+q]=C2[q]; Cv[12+q]=C3[q];
        }
        float s0=0.f, s1=0.f, s2=0.f, s3=0.f;
        #pragma unroll
        for (int n = 0; n < 16; ++n) {
            float a = __expf(dv*Av[n]);
            h[n] = fmaf(a, h[n], dxc*Bv[n]);
        }
        #pragma unroll
        for (int j = 0; j < 4; ++j) {
            s0 = fmaf(h[4*j+0], Cv[4*j+0], s0);
            s1 = fmaf(h[4*j+1], Cv[4*j+1], s1);
            s2 = fmaf(h[4*j+2], Cv[4*j+2], s2);
            s3 = fmaf(h[4*j+3], Cv[4*j+3], s3);
        }
        float contrib = (s0+s1)+(s2+s3);
        float zv = z[rowi*DIc + d];
        y[rowi*DIc + d] = __float2bfloat16((contrib + Dv*xcv) * siluf_(zv));
    }
}

// ---------------- GLU ----------------
__global__ void glu_kernel(const float* __restrict__ c2, float* __restrict__ out) {
    int idx = blockIdx.x*blockDim.x + threadIdx.x;
    if (idx >= Bc*Lc*Dc) return;
    int col = idx & (Dc-1); int row = idx >> 9;
    float a  = c2[(size_t)row*(2*Dc) + col];
    float gg = c2[(size_t)row*(2*Dc) + Dc + col];
    out[idx] = a * sigmoidf_(gg);
}

// ---------------- symmetric depthwise conv CK=31 + silu -> bf16 ----------------
__global__ void sym_conv_silu(const float* __restrict__ in, const float* __restrict__ w,
                              const float* __restrict__ bias, bf16* __restrict__ out) {
    int idx = blockIdx.x*blockDim.x + threadIdx.x;
    if (idx >= Bc*Lc*Dc) return;
    int d  = idx & (Dc-1);
    int bl = idx >> 9;
    int l  = bl & (Lc-1);
    float acc = bias[d];
    #pragma unroll
    for (int k = 0; k < CKc; ++k) {
        int ls = l - (CKc-1)/2 + k;
        if (ls >= 0 && ls < Lc)
            acc = fmaf(in[((size_t)(bl + ls - l))*Dc + d], w[d*CKc + k], acc);
    }
    out[idx] = __float2bfloat16(siluf_(acc));
}

extern "C" void kernel_launch(void* const* d_in, const int* in_sizes, int n_in,
                              void* d_out, int out_size, void* d_ws, size_t ws_size,
                              hipStream_t stream) {
    const float* x      = (const float*)d_in[0];
    const float* ln_g   = (const float*)d_in[1];
    const float* ln_b   = (const float*)d_in[2];
    const float* W_in   = (const float*)d_in[3];
    const float* conv_w = (const float*)d_in[4];
    const float* conv_b = (const float*)d_in[5];
    const float* W_x    = (const float*)d_in[6];
    const float* W_dt   = (const float*)d_in[7];
    const float* b_dt   = (const float*)d_in[8];
    const float* A_log  = (const float*)d_in[9];
    const float* Dp     = (const float*)d_in[10];
    const float* W_out  = (const float*)d_in[11];
    const float* cm_ln_g= (const float*)d_in[12];
    const float* cm_ln_b= (const float*)d_in[13];
    const float* pw1_w  = (const float*)d_in[14];
    const float* pw1_b  = (const float*)d_in[15];
    const float* dw_w   = (const float*)d_in[16];
    const float* dw_b   = (const float*)d_in[17];
    const float* pw2_w  = (const float*)d_in[18];
    const float* pw2_b  = (const float*)d_in[19];
    const float* ff_W1  = (const float*)d_in[20];
    const float* ff_b1  = (const float*)d_in[21];
    const float* ff_W2  = (const float*)d_in[22];
    const float* ff_b2  = (const float*)d_in[23];
    float* out = (float*)d_out;
    float* ws  = (float*)d_ws;

    // ---- workspace layout (float offsets), total 22,986,752 floats ~92 MB ----
    float* A_  = ws;                 // 4,194,304: xi f32 -> P(2M)+H(2M) -> c2 (4M)
    float* A2_ = ws + 4194304;       // 4,194,304: z f32 -> glu (2M)
    float* B_  = ws + 8388608;       // 4,194,304: xc f32 -> g1_bf16
    float* C_  = ws + 12582912;      //   262,144: dbl f32
    float* D_  = ws + 12845056;      // 4,194,304: delta -> m (2M)
    float* F_  = ws + 17039360;      // 1,572,864: dbl_bf16 / c_bf16 / cc_bf16 / f_bf16
    float* H_  = ws + 18612224;      // 2,097,152: h_bf16 / xc_bf16 / y_bf16
    float* J_  = ws + 20709376;      // 2,277,376: transposed bf16 weights

    float* xi_buf  = A_;
    float* P_buf   = A_;             // 64*32768 = 2,097,152
    float* H_buf   = A_ + 2097152;
    float* c2_buf  = A_;
    float* z_buf   = A2_;
    float* glu_buf = A2_;
    float* xc_buf  = B_;
    bf16*  g1b     = (bf16*)B_;
    float* dbl_buf = C_;
    float* dl_buf  = D_;
    float* m_buf   = D_;
    bf16*  dblb    = (bf16*)F_;
    bf16*  cb      = (bf16*)F_;
    bf16*  ccb     = (bf16*)F_;
    bf16*  fb      = (bf16*)F_;
    bf16*  hb      = (bf16*)H_;
    bf16*  xcb     = (bf16*)H_;
    bf16*  yb      = (bf16*)H_;
    float* f_buf   = out;            // f lives in d_out; GEMM15 reads it as residual

    bf16* Jw = (bf16*)J_;
    bf16* Win_t  = Jw;               // 2048 x 512
    bf16* Wx_t   = Jw + 1048576;     //   64 x 1024
    bf16* Wdt_t  = Jw + 1114112;     // 1024 x 32
    bf16* Wout_t = Jw + 1146880;     //  512 x 1024
    bf16* pw1_t  = Jw + 1671168;     // 1024 x 512
    bf16* pw2_t  = Jw + 2195456;     //  512 x 512
    bf16* ffW1_t = Jw + 2457600;     // 2048 x 512
    bf16* ffW2_t = Jw + 3506176;     //  512 x 2048

    const int M = Mrows;
    dim3 tw(32,8);

    // 0. weight transposes (f32 KxN -> bf16 NxK)
    wtrans<<<dim3(2048/32, 512/32), tw, 0, stream>>>(W_in,  Win_t,  512,  2048);
    wtrans<<<dim3(  64/32,1024/32), tw, 0, stream>>>(W_x,   Wx_t,   1024, 64);
    wtrans<<<dim3(1024/32,  32/32), tw, 0, stream>>>(W_dt,  Wdt_t,  32,   1024);
    wtrans<<<dim3( 512/32,1024/32), tw, 0, stream>>>(W_out, Wout_t, 1024, 512);
    wtrans<<<dim3(1024/32, 512/32), tw, 0, stream>>>(pw1_w, pw1_t,  512,  1024);
    wtrans<<<dim3( 512/32, 512/32), tw, 0, stream>>>(pw2_w, pw2_t,  512,  512);
    wtrans<<<dim3(2048/32, 512/32), tw, 0, stream>>>(ff_W1, ffW1_t, 512,  2048);
    wtrans<<<dim3( 512/32,2048/32), tw, 0, stream>>>(ff_W2, ffW2_t, 2048, 512);

    // 1. h = LN(x) -> bf16
    ln_kernel<false,true><<<M, 256, 0, stream>>>(x, ln_g, ln_b, nullptr, hb, Dc);
    // 2a. xi = h @ W_in[:, :DI]   2b. z = h @ W_in[:, DI:]
    mgemm<128,128,0,false,false,true,false><<<dim3(1024/128, M/128), 256, 0, stream>>>(
        hb, Dc, Win_t, nullptr, nullptr, xi_buf, nullptr, M, DIc, Dc);
    mgemm<128,128,0,false,false,true,false><<<dim3(1024/128, M/128), 256, 0, stream>>>(
        hb, Dc, Win_t + (size_t)DIc*Dc, nullptr, nullptr, z_buf, nullptr, M, DIc, Dc);
    // 3. xc = silu(causal dwconv(xi)) -> f32 + bf16
    causal_conv_silu<<<(M*DIc+255)/256, 256, 0, stream>>>(xi_buf, conv_w, conv_b, xc_buf, xcb);
    // 4. dbl = xc @ W_x  -> f32 + bf16
    mgemm<128,64,0,false,false,true,true><<<dim3(64/64, M/128), 256, 0, stream>>>(
        xcb, DIc, Wx_t, nullptr, nullptr, dbl_buf, dblb, M, 64, DIc);
    // 5. delta = softplus(dt @ W_dt + b_dt) -> f32
    mgemm<128,128,1,true,false,true,false><<<dim3(1024/128, M/128), 256, 0, stream>>>(
        dblb, 64, Wdt_t, b_dt, nullptr, dl_buf, nullptr, M, DIc, Rc);
    // 6. chunked selective scan -> y (bf16)
    scan_pass1<<<512, 256, 0, stream>>>(dl_buf, xc_buf, dbl_buf, A_log, P_buf, H_buf);
    scan_combine<<<128, 256, 0, stream>>>(P_buf, H_buf);
    scan_pass3<<<512, 256, 0, stream>>>(dl_buf, xc_buf, dbl_buf, z_buf, A_log, Dp, P_buf, yb);
    // 7. m = y @ W_out -> f32
    mgemm<128,128,0,false,false,true,false><<<dim3(512/128, M/128), 256, 0, stream>>>(
        yb, DIc, Wout_t, nullptr, nullptr, m_buf, nullptr, M, Dc, DIc);
    // 8. c = LN(m, cm) -> bf16
    ln_kernel<false,true><<<M, 256, 0, stream>>>(m_buf, cm_ln_g, cm_ln_b, nullptr, cb, Dc);
    // 9. c2 = c @ pw1 + b -> f32
    mgemm<128,128,0,true,false,true,false><<<dim3(1024/128, M/128), 256, 0, stream>>>(
        cb, Dc, pw1_t, pw1_b, nullptr, c2_buf, nullptr, M, 2*Dc, Dc);
    // 10. GLU -> f32
    glu_kernel<<<(M*Dc+255)/256, 256, 0, stream>>>(c2_buf, glu_buf);
    // 11. symmetric dwconv CK=31 + silu -> bf16
    sym_conv_silu<<<(M*Dc+255)/256, 256, 0, stream>>>(glu_buf, dw_w, dw_b, ccb);
    // 12. m = m + (cconv @ pw2 + b) -> f32 (in place)
    mgemm<128,128,0,true,true,true,false><<<dim3(512/128, M/128), 256, 0, stream>>>(
        ccb, Dc, pw2_t, pw2_b, m_buf, m_buf, nullptr, M, Dc, Dc);
    // 13. f = LN(m, ln) -> d_out (f32) + bf16
    ln_kernel<true,true><<<M, 256, 0, stream>>>(m_buf, ln_g, ln_b, f_buf, fb, Dc);
    // 14. g1 = gelu(f @ ff_W1 + b1) -> bf16
    mgemm<128,128,2,true,false,false,true><<<dim3(2048/128, M/128), 256, 0, stream>>>(
        fb, Dc, ffW1_t, ff_b1, nullptr, nullptr, g1b, M, DFFc, Dc);
    // 15. out = f + g1 @ ff_W2 + b2 -> d_out (in place: res tile == written tile)
    mgemm<128,128,0,true,true,true,false><<<dim3(512/128, M/128), 256, 0, stream>>>(
        g1b, DFFc, ffW2_t, ff_b2, f_buf, out, nullptr, M, Dc, DFFc);
}

// Round 6
// 305.429 us; speedup vs baseline: 10.2203x; 1.3068x over previous
//
#include <hip/hip_runtime.h>
#include <hip/hip_bf16.h>
#include <math.h>

// Problem constants
#define Bc   2
#define Lc   2048
#define Dc   512
#define DIc  1024
#define Nc   16
#define Kc   4
#define Rc   32
#define CKc  31
#define DFFc 2048
#define Mrows (Bc*Lc)   // 4096
#define CHUNK  32
#define NCHUNK 64

typedef __hip_bfloat16 bf16;
typedef short bf16x8 __attribute__((ext_vector_type(8)));
typedef float f32x4  __attribute__((ext_vector_type(4)));

__device__ __forceinline__ float sigmoidf_(float x){ return 1.f/(1.f+expf(-x)); }
__device__ __forceinline__ float siluf_(float x){ return x*sigmoidf_(x); }
__device__ __forceinline__ float softplusf_(float x){ return fmaxf(x,0.f)+log1pf(expf(-fabsf(x))); }
__device__ __forceinline__ float geluf_(float x){
    float x3 = x*x*x;
    return 0.5f*x*(1.f+tanhf(0.7978845608028654f*(x+0.044715f*x3)));
}

// async global -> LDS, 16 bytes/lane; lptr is wave-uniform base (HW adds lane*16)
__device__ __forceinline__ void gload16(const void* g, void* l) {
    __builtin_amdgcn_global_load_lds((const __attribute__((address_space(1))) void*)g,
                                     (__attribute__((address_space(3))) void*)l, 16, 0, 0);
}

// ---------------- LayerNorm (one block per row, D=512); optional f32/bf16 outs ----------------
template<bool WF, bool WB>
__global__ void ln_kernel(const float* __restrict__ in, const float* __restrict__ g,
                          const float* __restrict__ bb, float* __restrict__ outf,
                          bf16* __restrict__ outb, int D) {
    int row = blockIdx.x;
    const float* x = in + (size_t)row * D;
    float s = 0.f, s2 = 0.f;
    for (int i = threadIdx.x; i < D; i += blockDim.x) { float v = x[i]; s += v; s2 += v*v; }
    #pragma unroll
    for (int off = 32; off; off >>= 1) { s += __shfl_down(s, off); s2 += __shfl_down(s2, off); }
    __shared__ float sh[2][4];
    int wave = threadIdx.x >> 6, lane = threadIdx.x & 63;
    if (lane == 0) { sh[0][wave] = s; sh[1][wave] = s2; }
    __syncthreads();
    if (threadIdx.x == 0) {
        float ts = 0.f, ts2 = 0.f;
        int nw = blockDim.x >> 6;
        for (int w = 0; w < nw; ++w) { ts += sh[0][w]; ts2 += sh[1][w]; }
        sh[0][0] = ts; sh[1][0] = ts2;
    }
    __syncthreads();
    float mean = sh[0][0] / D;
    float var  = sh[1][0] / D - mean*mean;
    float rstd = rsqrtf(var + 1e-5f);
    for (int i = threadIdx.x; i < D; i += blockDim.x) {
        float v = (x[i]-mean)*rstd*g[i] + bb[i];
        if (WF) outf[(size_t)row*D + i] = v;
        if (WB) outb[(size_t)row*D + i] = __float2bfloat16(v);
    }
}

// ---------------- weight transpose+cast: W (K x N, f32) -> Wt (N x K, bf16) ----------------
__global__ void wtrans(const float* __restrict__ W, bf16* __restrict__ Wt, int K, int N) {
    __shared__ float t[32][33];
    int bx = blockIdx.x, by = blockIdx.y;
    int tx = threadIdx.x, ty = threadIdx.y;   // 32 x 8
    #pragma unroll
    for (int i = 0; i < 32; i += 8)
        t[ty+i][tx] = W[(size_t)(by*32+ty+i)*N + bx*32+tx];
    __syncthreads();
    #pragma unroll
    for (int i = 0; i < 32; i += 8)
        Wt[(size_t)(bx*32+ty+i)*K + by*32+tx] = __float2bfloat16(t[tx][ty+i]);
}

// ---------------- bf16 MFMA GEMM, 2-phase dbuf + global_load_lds + XOR swizzle ----------------
template<int BM, int BN, int ACT, bool BIAS, bool RES, bool WF32, bool WBF16>
__global__ __launch_bounds__(256) void mgemm(const bf16* __restrict__ A, int lda,
                                             const bf16* __restrict__ Wt,
                                             const float* __restrict__ bias,
                                             const float* __restrict__ res,
                                             float* __restrict__ outf,
                                             bf16* __restrict__ outb,
                                             int M, int N, int K) {
    constexpr int BK = 32;
    constexpr int WM = BM/2, WN = BN/2;       // per-wave tile
    constexpr int AM = WM/16, AN = WN/16;     // frags per wave
    constexpr int AISS = BM/64, BISS = BN/64; // 1KB staging issues per wave
    __shared__ __align__(16) bf16 As[2][BM*BK];
    __shared__ __align__(16) bf16 Bs[2][BN*BK];
    const int tid  = threadIdx.x;
    const int wave = tid >> 6, lane = tid & 63;
    const int r16  = lane & 15, kb = lane >> 4;
    // bijective XCD swizzle on flattened block id (nwg % 8 == 0 for all launches here)
    const int gx = gridDim.x;
    const int nwg = gx*gridDim.y;
    const int id  = blockIdx.y*gx + blockIdx.x;
    const int sid = (id & 7)*(nwg >> 3) + (id >> 3);
    const int bm = (sid / gx)*BM, bn = (sid % gx)*BN;
    const int wm = (wave>>1)*WM, wn = (wave&1)*WN;
    f32x4 acc[AM][AN] = {};
    const int nt = K / BK;

    // stage tile kt into buffer buf (async)
    auto stage = [&](int buf, int kt) {
        #pragma unroll
        for (int it = 0; it < AISS; ++it) {
            int base = (wave*AISS + it) << 10;          // wave-uniform byte base
            int Lb   = base + (lane << 4);              // this lane's dest byte
            int row  = Lb >> 6;
            int gch  = ((Lb >> 4) & 3) ^ (row & 3);     // inverse swizzle on source
            gload16(A + (size_t)(bm + row)*lda + kt*BK + gch*8, (char*)As[buf] + base);
        }
        #pragma unroll
        for (int it = 0; it < BISS; ++it) {
            int base = (wave*BISS + it) << 10;
            int Lb   = base + (lane << 4);
            int row  = Lb >> 6;
            int gch  = ((Lb >> 4) & 3) ^ (row & 3);
            gload16(Wt + (size_t)(bn + row)*K + kt*BK + gch*8, (char*)Bs[buf] + base);
        }
    };

    stage(0, 0);
    __syncthreads();
    for (int t = 0; t < nt; ++t) {
        int cur = t & 1;
        if (t + 1 < nt) stage(cur ^ 1, t + 1);
        bf16x8 af[AM], bfr[AN];
        #pragma unroll
        for (int mi = 0; mi < AM; ++mi) {
            int r = wm + mi*16 + r16;
            af[mi] = *(const bf16x8*)((const char*)As[cur] + r*64 + ((kb ^ (r & 3)) << 4));
        }
        #pragma unroll
        for (int ni = 0; ni < AN; ++ni) {
            int r = wn + ni*16 + r16;
            bfr[ni] = *(const bf16x8*)((const char*)Bs[cur] + r*64 + ((kb ^ (r & 3)) << 4));
        }
        #pragma unroll
        for (int mi = 0; mi < AM; ++mi)
            #pragma unroll
            for (int ni = 0; ni < AN; ++ni)
                acc[mi][ni] = __builtin_amdgcn_mfma_f32_16x16x32_bf16(af[mi], bfr[ni], acc[mi][ni], 0, 0, 0);
        __syncthreads();   // drains stage(t+1) DMA + all waves done reading buf[cur]
    }

    // epilogue: C/D map col=lane&15, row=(lane>>4)*4+r
    #pragma unroll
    for (int mi = 0; mi < AM; ++mi) {
        #pragma unroll
        for (int ni = 0; ni < AN; ++ni) {
            #pragma unroll
            for (int r = 0; r < 4; ++r) {
                int grow = bm + wm + mi*16 + kb*4 + r;
                int gcol = bn + wn + ni*16 + r16;
                float v = acc[mi][ni][r];
                if (BIAS) v += bias[gcol];
                if (ACT == 1) v = softplusf_(v);
                else if (ACT == 2) v = geluf_(v);
                if (RES) v += res[(size_t)grow*N + gcol];
                if (WF32)  outf[(size_t)grow*N + gcol] = v;
                if (WBF16) outb[(size_t)grow*N + gcol] = __float2bfloat16(v);
            }
        }
    }
}

// ---------------- causal depthwise conv K=4 + silu, sliding-window regs ----------------
// grid: (DIc/256, B, Lc/T); thread owns fixed d, T outputs along l.
template<int T>
__global__ __launch_bounds__(256) void causal_conv_silu(const float* __restrict__ xi, const float* __restrict__ w,
                                                        const float* __restrict__ bias, float* __restrict__ xc,
                                                        bf16* __restrict__ xcb) {
    int d  = blockIdx.x*256 + threadIdx.x;
    int b  = blockIdx.y;
    int l0 = blockIdx.z*T;
    const float* src = xi + (size_t)b*Lc*DIc + d;
    float wt[Kc];
    #pragma unroll
    for (int k = 0; k < Kc; ++k) wt[k] = w[d*Kc + k];
    float win[T + Kc - 1];
    #pragma unroll
    for (int i = 0; i < T + Kc - 1; ++i) {
        int li = l0 - (Kc-1) + i;
        win[i] = (li >= 0) ? src[(size_t)li*DIc] : 0.f;   // li < Lc guaranteed
    }
    float bv = bias[d];
    size_t obase = (size_t)b*Lc*DIc + (size_t)l0*DIc + d;
    #pragma unroll
    for (int o = 0; o < T; ++o) {
        float acc = bv;
        #pragma unroll
        for (int k = 0; k < Kc; ++k) acc = fmaf(win[o+k], wt[k], acc);
        float v = siluf_(acc);
        xc[obase + (size_t)o*DIc] = v;
        xcb[obase + (size_t)o*DIc] = __float2bfloat16(v);
    }
}

// ---------------- chunked selective scan, thread-per-channel, 16 states in registers ----------------
__global__ __launch_bounds__(256) void scan_pass1(const float* __restrict__ delta, const float* __restrict__ xc,
                                                  const float* __restrict__ dbl, const float* __restrict__ A_log,
                                                  float* __restrict__ P, float* __restrict__ H) {
    int dgroup = blockIdx.x & 3;
    int bc = blockIdx.x >> 2;           // 0..127
    int b = bc & 1, chunk = bc >> 1;    // chunk 0..63
    int d = dgroup*256 + threadIdx.x;
    float Av[16];
    #pragma unroll
    for (int j = 0; j < 4; ++j) {
        f32x4 v = *(const f32x4*)(&A_log[d*16 + 4*j]);
        #pragma unroll
        for (int q = 0; q < 4; ++q) Av[4*j+q] = -__expf(v[q]);
    }
    float h[16], Pl[16];
    #pragma unroll
    for (int n = 0; n < 16; ++n) { h[n] = 0.f; Pl[n] = 1.f; }
    size_t row0 = (size_t)b*Lc + (size_t)chunk*CHUNK;
    for (int i = 0; i < CHUNK; ++i) {
        size_t rowi = row0 + i;
        float dv  = delta[rowi*DIc + d];
        float xcv = xc[rowi*DIc + d];
        float dxc = dv*xcv;
        f32x4 B0 = *(const f32x4*)(&dbl[rowi*64 + Rc + 0]);
        f32x4 B1 = *(const f32x4*)(&dbl[rowi*64 + Rc + 4]);
        f32x4 B2 = *(const f32x4*)(&dbl[rowi*64 + Rc + 8]);
        f32x4 B3 = *(const f32x4*)(&dbl[rowi*64 + Rc + 12]);
        float Bv[16];
        #pragma unroll
        for (int q = 0; q < 4; ++q) { Bv[q]=B0[q]; Bv[4+q]=B1[q]; Bv[8+q]=B2[q]; Bv[12+q]=B3[q]; }
        #pragma unroll
        for (int n = 0; n < 16; ++n) {
            float a = __expf(dv*Av[n]);
            h[n] = fmaf(a, h[n], dxc*Bv[n]);
            Pl[n] *= a;
        }
    }
    size_t pidx = ((size_t)chunk*2048 + (size_t)b*DIc + d) * 16;
    #pragma unroll
    for (int j = 0; j < 4; ++j) {
        f32x4 vp, vh;
        #pragma unroll
        for (int q = 0; q < 4; ++q) { vp[q] = Pl[4*j+q]; vh[q] = h[4*j+q]; }
        *(f32x4*)(&P[pidx + 4*j]) = vp;
        *(f32x4*)(&H[pidx + 4*j]) = vh;
    }
}

// Serial combine across chunks; writes prefix state (hstart) back into P in place.
__global__ void scan_combine(float* __restrict__ P, const float* __restrict__ H) {
    int t = blockIdx.x*blockDim.x + threadIdx.x;  // 0..32767 = (b*DI+d)*16+n
    float h = 0.f;
    #pragma unroll
    for (int c = 0; c < NCHUNK; ++c) {
        size_t idx = (size_t)c*32768 + t;
        float Pv = P[idx], Hv = H[idx];
        P[idx] = h;                 // hstart for chunk c
        h = fmaf(Pv, h, Hv);
    }
}

__global__ __launch_bounds__(256) void scan_pass3(const float* __restrict__ delta, const float* __restrict__ xc,
                                                  const float* __restrict__ dbl, const float* __restrict__ z,
                                                  const float* __restrict__ A_log, const float* __restrict__ Dp,
                                                  const float* __restrict__ hstart, bf16* __restrict__ y) {
    int dgroup = blockIdx.x & 3;
    int bc = blockIdx.x >> 2;
    int b = bc & 1, chunk = bc >> 1;
    int d = dgroup*256 + threadIdx.x;
    float Av[16];
    #pragma unroll
    for (int j = 0; j < 4; ++j) {
        f32x4 v = *(const f32x4*)(&A_log[d*16 + 4*j]);
        #pragma unroll
        for (int q = 0; q < 4; ++q) Av[4*j+q] = -__expf(v[q]);
    }
    float Dv = Dp[d];
    float h[16];
    size_t pidx = ((size_t)chunk*2048 + (size_t)b*DIc + d) * 16;
    #pragma unroll
    for (int j = 0; j < 4; ++j) {
        f32x4 v = *(const f32x4*)(&hstart[pidx + 4*j]);
        #pragma unroll
        for (int q = 0; q < 4; ++q) h[4*j+q] = v[q];
    }
    size_t row0 = (size_t)b*Lc + (size_t)chunk*CHUNK;
    for (int i = 0; i < CHUNK; ++i) {
        size_t rowi = row0 + i;
        float dv  = delta[rowi*DIc + d];
        float xcv = xc[rowi*DIc + d];
        float dxc = dv*xcv;
        f32x4 B0 = *(const f32x4*)(&dbl[rowi*64 + Rc + 0]);
        f32x4 B1 = *(const f32x4*)(&dbl[rowi*64 + Rc + 4]);
        f32x4 B2 = *(const f32x4*)(&dbl[rowi*64 + Rc + 8]);
        f32x4 B3 = *(const f32x4*)(&dbl[rowi*64 + Rc + 12]);
        f32x4 C0 = *(const f32x4*)(&dbl[rowi*64 + Rc + Nc + 0]);
        f32x4 C1 = *(const f32x4*)(&dbl[rowi*64 + Rc + Nc + 4]);
        f32x4 C2 = *(const f32x4*)(&dbl[rowi*64 + Rc + Nc + 8]);
        f32x4 C3 = *(const f32x4*)(&dbl[rowi*64 + Rc + Nc + 12]);
        float Bv[16], Cv[16];
        #pragma unroll
        for (int q = 0; q < 4; ++q) {
            Bv[q]=B0[q]; Bv[4+q]=B1[q]; Bv[8+q]=B2[q]; Bv[12+q]=B3[q];
            Cv[q]=C0[q]; Cv[4+q]=C1[q]; Cv[8+q]=C2[q]; Cv[12+q]=C3[q];
        }
        float s0=0.f, s1=0.f, s2=0.f, s3=0.f;
        #pragma unroll
        for (int n = 0; n < 16; ++n) {
            float a = __expf(dv*Av[n]);
            h[n] = fmaf(a, h[n], dxc*Bv[n]);
        }
        #pragma unroll
        for (int j = 0; j < 4; ++j) {
            s0 = fmaf(h[4*j+0], Cv[4*j+0], s0);
            s1 = fmaf(h[4*j+1], Cv[4*j+1], s1);
            s2 = fmaf(h[4*j+2], Cv[4*j+2], s2);
            s3 = fmaf(h[4*j+3], Cv[4*j+3], s3);
        }
        float contrib = (s0+s1)+(s2+s3);
        float zv = z[rowi*DIc + d];
        y[rowi*DIc + d] = __float2bfloat16((contrib + Dv*xcv) * siluf_(zv));
    }
}

// ---------------- GLU ----------------
__global__ void glu_kernel(const float* __restrict__ c2, float* __restrict__ out) {
    int idx = blockIdx.x*blockDim.x + threadIdx.x;
    if (idx >= Bc*Lc*Dc) return;
    int col = idx & (Dc-1); int row = idx >> 9;
    float a  = c2[(size_t)row*(2*Dc) + col];
    float gg = c2[(size_t)row*(2*Dc) + Dc + col];
    out[idx] = a * sigmoidf_(gg);
}

// ---------------- symmetric depthwise conv CK=31 + silu, sliding-window regs ----------------
// grid: (Dc/256, B, Lc/T); thread owns fixed d, T outputs along l.
template<int T>
__global__ __launch_bounds__(256) void sym_conv_silu(const float* __restrict__ in, const float* __restrict__ w,
                                                     const float* __restrict__ bias, bf16* __restrict__ out) {
    int d  = blockIdx.x*256 + threadIdx.x;
    int b  = blockIdx.y;
    int l0 = blockIdx.z*T;
    const float* src = in + (size_t)b*Lc*Dc + d;
    float wt[CKc];
    #pragma unroll
    for (int k = 0; k < CKc; ++k) wt[k] = w[d*CKc + k];
    constexpr int HALF = (CKc-1)/2;   // 15
    float win[T + CKc - 1];
    #pragma unroll
    for (int i = 0; i < T + CKc - 1; ++i) {
        int li = l0 - HALF + i;
        win[i] = (li >= 0 && li < Lc) ? src[(size_t)li*Dc] : 0.f;
    }
    float bv = bias[d];
    size_t obase = (size_t)b*Lc*Dc + (size_t)l0*Dc + d;
    #pragma unroll
    for (int o = 0; o < T; ++o) {
        float acc = bv;
        #pragma unroll
        for (int k = 0; k < CKc; ++k) acc = fmaf(win[o+k], wt[k], acc);
        out[obase + (size_t)o*Dc] = __float2bfloat16(siluf_(acc));
    }
}

extern "C" void kernel_launch(void* const* d_in, const int* in_sizes, int n_in,
                              void* d_out, int out_size, void* d_ws, size_t ws_size,
                              hipStream_t stream) {
    const float* x      = (const float*)d_in[0];
    const float* ln_g   = (const float*)d_in[1];
    const float* ln_b   = (const float*)d_in[2];
    const float* W_in   = (const float*)d_in[3];
    const float* conv_w = (const float*)d_in[4];
    const float* conv_b = (const float*)d_in[5];
    const float* W_x    = (const float*)d_in[6];
    const float* W_dt   = (const float*)d_in[7];
    const float* b_dt   = (const float*)d_in[8];
    const float* A_log  = (const float*)d_in[9];
    const float* Dp     = (const float*)d_in[10];
    const float* W_out  = (const float*)d_in[11];
    const float* cm_ln_g= (const float*)d_in[12];
    const float* cm_ln_b= (const float*)d_in[13];
    const float* pw1_w  = (const float*)d_in[14];
    const float* pw1_b  = (const float*)d_in[15];
    const float* dw_w   = (const float*)d_in[16];
    const float* dw_b   = (const float*)d_in[17];
    const float* pw2_w  = (const float*)d_in[18];
    const float* pw2_b  = (const float*)d_in[19];
    const float* ff_W1  = (const float*)d_in[20];
    const float* ff_b1  = (const float*)d_in[21];
    const float* ff_W2  = (const float*)d_in[22];
    const float* ff_b2  = (const float*)d_in[23];
    float* out = (float*)d_out;
    float* ws  = (float*)d_ws;

    // ---- workspace layout (float offsets), total 22,986,752 floats ~92 MB ----
    float* A_  = ws;                 // 4,194,304: xi f32 -> P(2M)+H(2M) -> c2 (4M)
    float* A2_ = ws + 4194304;       // 4,194,304: z f32 -> glu (2M)
    float* B_  = ws + 8388608;       // 4,194,304: xc f32 -> g1_bf16
    float* C_  = ws + 12582912;      //   262,144: dbl f32
    float* D_  = ws + 12845056;      // 4,194,304: delta -> m (2M)
    float* F_  = ws + 17039360;      // 1,572,864: dbl_bf16 / c_bf16 / cc_bf16 / f_bf16
    float* H_  = ws + 18612224;      // 2,097,152: h_bf16 / xc_bf16 / y_bf16
    float* J_  = ws + 20709376;      // 2,277,376: transposed bf16 weights

    float* xi_buf  = A_;
    float* P_buf   = A_;             // 64*32768 = 2,097,152
    float* H_buf   = A_ + 2097152;
    float* c2_buf  = A_;
    float* z_buf   = A2_;
    float* glu_buf = A2_;
    float* xc_buf  = B_;
    bf16*  g1b     = (bf16*)B_;
    float* dbl_buf = C_;
    float* dl_buf  = D_;
    float* m_buf   = D_;
    bf16*  dblb    = (bf16*)F_;
    bf16*  cb      = (bf16*)F_;
    bf16*  ccb     = (bf16*)F_;
    bf16*  fb      = (bf16*)F_;
    bf16*  hb      = (bf16*)H_;
    bf16*  xcb     = (bf16*)H_;
    bf16*  yb      = (bf16*)H_;
    float* f_buf   = out;            // f lives in d_out; GEMM15 reads it as residual

    bf16* Jw = (bf16*)J_;
    bf16* Win_t  = Jw;               // 2048 x 512
    bf16* Wx_t   = Jw + 1048576;     //   64 x 1024
    bf16* Wdt_t  = Jw + 1114112;     // 1024 x 32
    bf16* Wout_t = Jw + 1146880;     //  512 x 1024
    bf16* pw1_t  = Jw + 1671168;     // 1024 x 512
    bf16* pw2_t  = Jw + 2195456;     //  512 x 512
    bf16* ffW1_t = Jw + 2457600;     // 2048 x 512
    bf16* ffW2_t = Jw + 3506176;     //  512 x 2048

    const int M = Mrows;
    dim3 tw(32,8);

    // 0. weight transposes (f32 KxN -> bf16 NxK)
    wtrans<<<dim3(2048/32, 512/32), tw, 0, stream>>>(W_in,  Win_t,  512,  2048);
    wtrans<<<dim3(  64/32,1024/32), tw, 0, stream>>>(W_x,   Wx_t,   1024, 64);
    wtrans<<<dim3(1024/32,  32/32), tw, 0, stream>>>(W_dt,  Wdt_t,  32,   1024);
    wtrans<<<dim3( 512/32,1024/32), tw, 0, stream>>>(W_out, Wout_t, 1024, 512);
    wtrans<<<dim3(1024/32, 512/32), tw, 0, stream>>>(pw1_w, pw1_t,  512,  1024);
    wtrans<<<dim3( 512/32, 512/32), tw, 0, stream>>>(pw2_w, pw2_t,  512,  512);
    wtrans<<<dim3(2048/32, 512/32), tw, 0, stream>>>(ff_W1, ffW1_t, 512,  2048);
    wtrans<<<dim3( 512/32,2048/32), tw, 0, stream>>>(ff_W2, ffW2_t, 2048, 512);

    // 1. h = LN(x) -> bf16
    ln_kernel<false,true><<<M, 256, 0, stream>>>(x, ln_g, ln_b, nullptr, hb, Dc);
    // 2a. xi = h @ W_in[:, :DI]   2b. z = h @ W_in[:, DI:]
    mgemm<128,128,0,false,false,true,false><<<dim3(1024/128, M/128), 256, 0, stream>>>(
        hb, Dc, Win_t, nullptr, nullptr, xi_buf, nullptr, M, DIc, Dc);
    mgemm<128,128,0,false,false,true,false><<<dim3(1024/128, M/128), 256, 0, stream>>>(
        hb, Dc, Win_t + (size_t)DIc*Dc, nullptr, nullptr, z_buf, nullptr, M, DIc, Dc);
    // 3. xc = silu(causal dwconv(xi)) -> f32 + bf16   (sliding window, T=16)
    causal_conv_silu<16><<<dim3(DIc/256, Bc, Lc/16), 256, 0, stream>>>(xi_buf, conv_w, conv_b, xc_buf, xcb);
    // 4. dbl = xc @ W_x  -> f32 + bf16
    mgemm<128,64,0,false,false,true,true><<<dim3(64/64, M/128), 256, 0, stream>>>(
        xcb, DIc, Wx_t, nullptr, nullptr, dbl_buf, dblb, M, 64, DIc);
    // 5. delta = softplus(dt @ W_dt + b_dt) -> f32
    mgemm<128,128,1,true,false,true,false><<<dim3(1024/128, M/128), 256, 0, stream>>>(
        dblb, 64, Wdt_t, b_dt, nullptr, dl_buf, nullptr, M, DIc, Rc);
    // 6. chunked selective scan -> y (bf16)
    scan_pass1<<<512, 256, 0, stream>>>(dl_buf, xc_buf, dbl_buf, A_log, P_buf, H_buf);
    scan_combine<<<128, 256, 0, stream>>>(P_buf, H_buf);
    scan_pass3<<<512, 256, 0, stream>>>(dl_buf, xc_buf, dbl_buf, z_buf, A_log, Dp, P_buf, yb);
    // 7. m = y @ W_out -> f32
    mgemm<128,128,0,false,false,true,false><<<dim3(512/128, M/128), 256, 0, stream>>>(
        yb, DIc, Wout_t, nullptr, nullptr, m_buf, nullptr, M, Dc, DIc);
    // 8. c = LN(m, cm) -> bf16
    ln_kernel<false,true><<<M, 256, 0, stream>>>(m_buf, cm_ln_g, cm_ln_b, nullptr, cb, Dc);
    // 9. c2 = c @ pw1 + b -> f32
    mgemm<128,128,0,true,false,true,false><<<dim3(1024/128, M/128), 256, 0, stream>>>(
        cb, Dc, pw1_t, pw1_b, nullptr, c2_buf, nullptr, M, 2*Dc, Dc);
    // 10. GLU -> f32
    glu_kernel<<<(M*Dc+255)/256, 256, 0, stream>>>(c2_buf, glu_buf);
    // 11. symmetric dwconv CK=31 + silu -> bf16   (sliding window, T=16)
    sym_conv_silu<16><<<dim3(Dc/256, Bc, Lc/16), 256, 0, stream>>>(glu_buf, dw_w, dw_b, ccb);
    // 12. m = m + (cconv @ pw2 + b) -> f32 (in place)
    mgemm<128,128,0,true,true,true,false><<<dim3(512/128, M/128), 256, 0, stream>>>(
        ccb, Dc, pw2_t, pw2_b, m_buf, m_buf, nullptr, M, Dc, Dc);
    // 13. f = LN(m, ln) -> d_out (f32) + bf16
    ln_kernel<true,true><<<M, 256, 0, stream>>>(m_buf, ln_g, ln_b, f_buf, fb, Dc);
    // 14. g1 = gelu(f @ ff_W1 + b1) -> bf16
    mgemm<128,128,2,true,false,false,true><<<dim3(2048/128, M/128), 256, 0, stream>>>(
        fb, Dc, ffW1_t, ff_b1, nullptr, nullptr, g1b, M, DFFc, Dc);
    // 15. out = f + g1 @ ff_W2 + b2 -> d_out (in place: res tile == written tile)
    mgemm<128,128,0,true,true,true,false><<<dim3(512/128, M/128), 256, 0, stream>>>(
        g1b, DFFc, ffW2_t, ff_b2, f_buf, out, nullptr, M, Dc, DFFc);
}

// Round 7
// 260.984 us; speedup vs baseline: 11.9608x; 1.1703x over previous
//
#include <hip/hip_runtime.h>
#include <hip/hip_bf16.h>
#include <math.h>

// Problem constants
#define Bc   2
#define Lc   2048
#define Dc   512
#define DIc  1024
#define Nc   16
#define Kc   4
#define Rc   32
#define CKc  31
#define DFFc 2048
#define Mrows (Bc*Lc)   // 4096
#define CHUNK  32
#define NCHUNK 64

typedef __hip_bfloat16 bf16;
typedef short bf16x8 __attribute__((ext_vector_type(8)));
typedef float f32x4  __attribute__((ext_vector_type(4)));

__device__ __forceinline__ float sigmoidf_(float x){ return 1.f/(1.f+expf(-x)); }
__device__ __forceinline__ float siluf_(float x){ return x*sigmoidf_(x); }
__device__ __forceinline__ float softplusf_(float x){ return fmaxf(x,0.f)+log1pf(expf(-fabsf(x))); }
__device__ __forceinline__ float geluf_(float x){
    float x3 = x*x*x;
    return 0.5f*x*(1.f+tanhf(0.7978845608028654f*(x+0.044715f*x3)));
}

// async global -> LDS, 16 bytes/lane; lptr is wave-uniform base (HW adds lane*16)
__device__ __forceinline__ void gload16(const void* g, void* l) {
    __builtin_amdgcn_global_load_lds((const __attribute__((address_space(1))) void*)g,
                                     (__attribute__((address_space(3))) void*)l, 16, 0, 0);
}

// ---------------- LayerNorm (one block per row, D=512); optional f32/bf16 outs ----------------
template<bool WF, bool WB>
__global__ void ln_kernel(const float* __restrict__ in, const float* __restrict__ g,
                          const float* __restrict__ bb, float* __restrict__ outf,
                          bf16* __restrict__ outb, int D) {
    int row = blockIdx.x;
    const float* x = in + (size_t)row * D;
    float s = 0.f, s2 = 0.f;
    for (int i = threadIdx.x; i < D; i += blockDim.x) { float v = x[i]; s += v; s2 += v*v; }
    #pragma unroll
    for (int off = 32; off; off >>= 1) { s += __shfl_down(s, off); s2 += __shfl_down(s2, off); }
    __shared__ float sh[2][4];
    int wave = threadIdx.x >> 6, lane = threadIdx.x & 63;
    if (lane == 0) { sh[0][wave] = s; sh[1][wave] = s2; }
    __syncthreads();
    if (threadIdx.x == 0) {
        float ts = 0.f, ts2 = 0.f;
        int nw = blockDim.x >> 6;
        for (int w = 0; w < nw; ++w) { ts += sh[0][w]; ts2 += sh[1][w]; }
        sh[0][0] = ts; sh[1][0] = ts2;
    }
    __syncthreads();
    float mean = sh[0][0] / D;
    float var  = sh[1][0] / D - mean*mean;
    float rstd = rsqrtf(var + 1e-5f);
    for (int i = threadIdx.x; i < D; i += blockDim.x) {
        float v = (x[i]-mean)*rstd*g[i] + bb[i];
        if (WF) outf[(size_t)row*D + i] = v;
        if (WB) outb[(size_t)row*D + i] = __float2bfloat16(v);
    }
}

// ---------------- weight transpose+cast: W (K x N, f32) -> Wt (N x K, bf16) ----------------
__global__ void wtrans(const float* __restrict__ W, bf16* __restrict__ Wt, int K, int N) {
    __shared__ float t[32][33];
    int bx = blockIdx.x, by = blockIdx.y;
    int tx = threadIdx.x, ty = threadIdx.y;   // 32 x 8
    #pragma unroll
    for (int i = 0; i < 32; i += 8)
        t[ty+i][tx] = W[(size_t)(by*32+ty+i)*N + bx*32+tx];
    __syncthreads();
    #pragma unroll
    for (int i = 0; i < 32; i += 8)
        Wt[(size_t)(bx*32+ty+i)*K + by*32+tx] = __float2bfloat16(t[tx][ty+i]);
}

// ---------------- bf16 MFMA GEMM, 64x64 tile, 2-phase dbuf + global_load_lds + XOR swizzle ----------------
// A: M x K bf16 (row stride lda), Wt: N x K bf16. out = act(A@Wt^T + bias) (+res).
// SPLITK>1: grid.z splits K; raw fp32 partials to outf + z*M*N (no bias/act/res).
template<int BM, int BN, int SPLITK, int ACT, bool BIAS, bool RES, bool WF32, bool WBF16>
__global__ __launch_bounds__(256) void mgemm(const bf16* __restrict__ A, int lda,
                                             const bf16* __restrict__ Wt,
                                             const float* __restrict__ bias,
                                             const float* __restrict__ res,
                                             float* __restrict__ outf,
                                             bf16* __restrict__ outb,
                                             int M, int N, int K) {
    constexpr int BK = 32;
    constexpr int WM = BM/2, WN = BN/2;       // per-wave tile (2x2 wave grid)
    constexpr int AM = WM/16, AN = WN/16;     // frags per wave
    constexpr int AISS = BM/64, BISS = BN/64; // 1KB staging issues per wave
    __shared__ __align__(16) bf16 As[2][BM*BK];
    __shared__ __align__(16) bf16 Bs[2][BN*BK];
    const int tid  = threadIdx.x;
    const int wave = tid >> 6, lane = tid & 63;
    const int r16  = lane & 15, kb = lane >> 4;
    // bijective XCD swizzle on flattened (x,y) block id (nwg % 8 == 0 for all launches here)
    const int gx = gridDim.x;
    const int nwg = gx*gridDim.y;
    const int id  = blockIdx.y*gx + blockIdx.x;
    const int sid = (id & 7)*(nwg >> 3) + (id >> 3);
    const int bm = (sid / gx)*BM, bn = (sid % gx)*BN;
    const int wm = (wave>>1)*WM, wn = (wave&1)*WN;
    const int Keff = K / SPLITK;
    const int kz0  = (SPLITK > 1) ? blockIdx.z * Keff : 0;
    f32x4 acc[AM][AN] = {};
    const int nt = Keff / BK;

    // stage tile kt into buffer buf (async)
    auto stage = [&](int buf, int kt) {
        #pragma unroll
        for (int it = 0; it < AISS; ++it) {
            int base = (wave*AISS + it) << 10;          // wave-uniform byte base
            int Lb   = base + (lane << 4);              // this lane's dest byte
            int row  = Lb >> 6;
            int gch  = ((Lb >> 4) & 3) ^ (row & 3);     // inverse swizzle on source
            gload16(A + (size_t)(bm + row)*lda + kz0 + kt*BK + gch*8, (char*)As[buf] + base);
        }
        #pragma unroll
        for (int it = 0; it < BISS; ++it) {
            int base = (wave*BISS + it) << 10;
            int Lb   = base + (lane << 4);
            int row  = Lb >> 6;
            int gch  = ((Lb >> 4) & 3) ^ (row & 3);
            gload16(Wt + (size_t)(bn + row)*K + kz0 + kt*BK + gch*8, (char*)Bs[buf] + base);
        }
    };

    stage(0, 0);
    __syncthreads();
    for (int t = 0; t < nt; ++t) {
        int cur = t & 1;
        if (t + 1 < nt) stage(cur ^ 1, t + 1);
        bf16x8 af[AM], bfr[AN];
        #pragma unroll
        for (int mi = 0; mi < AM; ++mi) {
            int r = wm + mi*16 + r16;
            af[mi] = *(const bf16x8*)((const char*)As[cur] + r*64 + ((kb ^ (r & 3)) << 4));
        }
        #pragma unroll
        for (int ni = 0; ni < AN; ++ni) {
            int r = wn + ni*16 + r16;
            bfr[ni] = *(const bf16x8*)((const char*)Bs[cur] + r*64 + ((kb ^ (r & 3)) << 4));
        }
        #pragma unroll
        for (int mi = 0; mi < AM; ++mi)
            #pragma unroll
            for (int ni = 0; ni < AN; ++ni)
                acc[mi][ni] = __builtin_amdgcn_mfma_f32_16x16x32_bf16(af[mi], bfr[ni], acc[mi][ni], 0, 0, 0);
        __syncthreads();   // drains stage(t+1) DMA + all waves done reading buf[cur]
    }

    // epilogue: C/D map col=lane&15, row=(lane>>4)*4+r
    #pragma unroll
    for (int mi = 0; mi < AM; ++mi) {
        #pragma unroll
        for (int ni = 0; ni < AN; ++ni) {
            #pragma unroll
            for (int r = 0; r < 4; ++r) {
                int grow = bm + wm + mi*16 + kb*4 + r;
                int gcol = bn + wn + ni*16 + r16;
                float v = acc[mi][ni][r];
                if (SPLITK > 1) {
                    outf[(size_t)blockIdx.z*M*N + (size_t)grow*N + gcol] = v;
                } else {
                    if (BIAS) v += bias[gcol];
                    if (ACT == 1) v = softplusf_(v);
                    else if (ACT == 2) v = geluf_(v);
                    if (RES) v += res[(size_t)grow*N + gcol];
                    if (WF32)  outf[(size_t)grow*N + gcol] = v;
                    if (WBF16) outb[(size_t)grow*N + gcol] = __float2bfloat16(v);
                }
            }
        }
    }
}

// sum SPLITK partials -> f32 + bf16
__global__ void splitk_combine(const float* __restrict__ part, float* __restrict__ outf,
                               bf16* __restrict__ outb, int n, int parts) {
    int i = blockIdx.x*256 + threadIdx.x;
    if (i >= n) return;
    float s = 0.f;
    for (int p = 0; p < parts; ++p) s += part[(size_t)p*n + i];
    outf[i] = s;
    outb[i] = __float2bfloat16(s);
}

// ---------------- causal depthwise conv K=4 + silu, sliding-window regs ----------------
template<int T>
__global__ __launch_bounds__(256) void causal_conv_silu(const float* __restrict__ xi, const float* __restrict__ w,
                                                        const float* __restrict__ bias, float* __restrict__ xc,
                                                        bf16* __restrict__ xcb) {
    int d  = blockIdx.x*256 + threadIdx.x;
    int b  = blockIdx.y;
    int l0 = blockIdx.z*T;
    const float* src = xi + (size_t)b*Lc*DIc + d;
    float wt[Kc];
    #pragma unroll
    for (int k = 0; k < Kc; ++k) wt[k] = w[d*Kc + k];
    float win[T + Kc - 1];
    #pragma unroll
    for (int i = 0; i < T + Kc - 1; ++i) {
        int li = l0 - (Kc-1) + i;
        win[i] = (li >= 0) ? src[(size_t)li*DIc] : 0.f;   // li < Lc guaranteed
    }
    float bv = bias[d];
    size_t obase = (size_t)b*Lc*DIc + (size_t)l0*DIc + d;
    #pragma unroll
    for (int o = 0; o < T; ++o) {
        float acc = bv;
        #pragma unroll
        for (int k = 0; k < Kc; ++k) acc = fmaf(win[o+k], wt[k], acc);
        float v = siluf_(acc);
        xc[obase + (size_t)o*DIc] = v;
        xcb[obase + (size_t)o*DIc] = __float2bfloat16(v);
    }
}

// ---------------- chunked selective scan, thread-per-channel, 16 states in registers ----------------
__global__ __launch_bounds__(256) void scan_pass1(const float* __restrict__ delta, const float* __restrict__ xc,
                                                  const float* __restrict__ dbl, const float* __restrict__ A_log,
                                                  float* __restrict__ P, float* __restrict__ H) {
    int dgroup = blockIdx.x & 3;
    int bc = blockIdx.x >> 2;           // 0..127
    int b = bc & 1, chunk = bc >> 1;    // chunk 0..63
    int d = dgroup*256 + threadIdx.x;
    float Av[16];
    #pragma unroll
    for (int j = 0; j < 4; ++j) {
        f32x4 v = *(const f32x4*)(&A_log[d*16 + 4*j]);
        #pragma unroll
        for (int q = 0; q < 4; ++q) Av[4*j+q] = -__expf(v[q]);
    }
    float h[16], Pl[16];
    #pragma unroll
    for (int n = 0; n < 16; ++n) { h[n] = 0.f; Pl[n] = 1.f; }
    size_t row0 = (size_t)b*Lc + (size_t)chunk*CHUNK;
    for (int i = 0; i < CHUNK; ++i) {
        size_t rowi = row0 + i;
        float dv  = delta[rowi*DIc + d];
        float xcv = xc[rowi*DIc + d];
        float dxc = dv*xcv;
        f32x4 B0 = *(const f32x4*)(&dbl[rowi*64 + Rc + 0]);
        f32x4 B1 = *(const f32x4*)(&dbl[rowi*64 + Rc + 4]);
        f32x4 B2 = *(const f32x4*)(&dbl[rowi*64 + Rc + 8]);
        f32x4 B3 = *(const f32x4*)(&dbl[rowi*64 + Rc + 12]);
        float Bv[16];
        #pragma unroll
        for (int q = 0; q < 4; ++q) { Bv[q]=B0[q]; Bv[4+q]=B1[q]; Bv[8+q]=B2[q]; Bv[12+q]=B3[q]; }
        #pragma unroll
        for (int n = 0; n < 16; ++n) {
            float a = __expf(dv*Av[n]);
            h[n] = fmaf(a, h[n], dxc*Bv[n]);
            Pl[n] *= a;
        }
    }
    size_t pidx = ((size_t)chunk*2048 + (size_t)b*DIc + d) * 16;
    #pragma unroll
    for (int j = 0; j < 4; ++j) {
        f32x4 vp, vh;
        #pragma unroll
        for (int q = 0; q < 4; ++q) { vp[q] = Pl[4*j+q]; vh[q] = h[4*j+q]; }
        *(f32x4*)(&P[pidx + 4*j]) = vp;
        *(f32x4*)(&H[pidx + 4*j]) = vh;
    }
}

// Serial combine across chunks; writes prefix state (hstart) back into P in place.
__global__ void scan_combine(float* __restrict__ P, const float* __restrict__ H) {
    int t = blockIdx.x*blockDim.x + threadIdx.x;  // 0..32767 = (b*DI+d)*16+n
    float h = 0.f;
    #pragma unroll
    for (int c = 0; c < NCHUNK; ++c) {
        size_t idx = (size_t)c*32768 + t;
        float Pv = P[idx], Hv = H[idx];
        P[idx] = h;                 // hstart for chunk c
        h = fmaf(Pv, h, Hv);
    }
}

__global__ __launch_bounds__(256) void scan_pass3(const float* __restrict__ delta, const float* __restrict__ xc,
                                                  const float* __restrict__ dbl, const float* __restrict__ z,
                                                  const float* __restrict__ A_log, const float* __restrict__ Dp,
                                                  const float* __restrict__ hstart, bf16* __restrict__ y) {
    int dgroup = blockIdx.x & 3;
    int bc = blockIdx.x >> 2;
    int b = bc & 1, chunk = bc >> 1;
    int d = dgroup*256 + threadIdx.x;
    float Av[16];
    #pragma unroll
    for (int j = 0; j < 4; ++j) {
        f32x4 v = *(const f32x4*)(&A_log[d*16 + 4*j]);
        #pragma unroll
        for (int q = 0; q < 4; ++q) Av[4*j+q] = -__expf(v[q]);
    }
    float Dv = Dp[d];
    float h[16];
    size_t pidx = ((size_t)chunk*2048 + (size_t)b*DIc + d) * 16;
    #pragma unroll
    for (int j = 0; j < 4; ++j) {
        f32x4 v = *(const f32x4*)(&hstart[pidx + 4*j]);
        #pragma unroll
        for (int q = 0; q < 4; ++q) h[4*j+q] = v[q];
    }
    size_t row0 = (size_t)b*Lc + (size_t)chunk*CHUNK;
    for (int i = 0; i < CHUNK; ++i) {
        size_t rowi = row0 + i;
        float dv  = delta[rowi*DIc + d];
        float xcv = xc[rowi*DIc + d];
        float dxc = dv*xcv;
        f32x4 B0 = *(const f32x4*)(&dbl[rowi*64 + Rc + 0]);
        f32x4 B1 = *(const f32x4*)(&dbl[rowi*64 + Rc + 4]);
        f32x4 B2 = *(const f32x4*)(&dbl[rowi*64 + Rc + 8]);
        f32x4 B3 = *(const f32x4*)(&dbl[rowi*64 + Rc + 12]);
        f32x4 C0 = *(const f32x4*)(&dbl[rowi*64 + Rc + Nc + 0]);
        f32x4 C1 = *(const f32x4*)(&dbl[rowi*64 + Rc + Nc + 4]);
        f32x4 C2 = *(const f32x4*)(&dbl[rowi*64 + Rc + Nc + 8]);
        f32x4 C3 = *(const f32x4*)(&dbl[rowi*64 + Rc + Nc + 12]);
        float Bv[16], Cv[16];
        #pragma unroll
        for (int q = 0; q < 4; ++q) {
            Bv[q]=B0[q]; Bv[4+q]=B1[q]; Bv[8+q]=B2[q]; Bv[12+q]=B3[q];
            Cv[q]=C0[q]; Cv[4+q]=C1[q]; Cv[8+q]=C2[q]; Cv[12+q]=C3[q];
        }
        float s0=0.f, s1=0.f, s2=0.f, s3=0.f;
        #pragma unroll
        for (int n = 0; n < 16; ++n) {
            float a = __expf(dv*Av[n]);
            h[n] = fmaf(a, h[n], dxc*Bv[n]);
        }
        #pragma unroll
        for (int j = 0; j < 4; ++j) {
            s0 = fmaf(h[4*j+0], Cv[4*j+0], s0);
            s1 = fmaf(h[4*j+1], Cv[4*j+1], s1);
            s2 = fmaf(h[4*j+2], Cv[4*j+2], s2);
            s3 = fmaf(h[4*j+3], Cv[4*j+3], s3);
        }
        float contrib = (s0+s1)+(s2+s3);
        float zv = z[rowi*DIc + d];
        y[rowi*DIc + d] = __float2bfloat16((contrib + Dv*xcv) * siluf_(zv));
    }
}

// ---------------- GLU ----------------
__global__ void glu_kernel(const float* __restrict__ c2, float* __restrict__ out) {
    int idx = blockIdx.x*blockDim.x + threadIdx.x;
    if (idx >= Bc*Lc*Dc) return;
    int col = idx & (Dc-1); int row = idx >> 9;
    float a  = c2[(size_t)row*(2*Dc) + col];
    float gg = c2[(size_t)row*(2*Dc) + Dc + col];
    out[idx] = a * sigmoidf_(gg);
}

// ---------------- symmetric depthwise conv CK=31 + silu, sliding-window regs ----------------
template<int T>
__global__ __launch_bounds__(256) void sym_conv_silu(const float* __restrict__ in, const float* __restrict__ w,
                                                     const float* __restrict__ bias, bf16* __restrict__ out) {
    int d  = blockIdx.x*256 + threadIdx.x;
    int b  = blockIdx.y;
    int l0 = blockIdx.z*T;
    const float* src = in + (size_t)b*Lc*Dc + d;
    float wt[CKc];
    #pragma unroll
    for (int k = 0; k < CKc; ++k) wt[k] = w[d*CKc + k];
    constexpr int HALF = (CKc-1)/2;   // 15
    float win[T + CKc - 1];
    #pragma unroll
    for (int i = 0; i < T + CKc - 1; ++i) {
        int li = l0 - HALF + i;
        win[i] = (li >= 0 && li < Lc) ? src[(size_t)li*Dc] : 0.f;
    }
    float bv = bias[d];
    size_t obase = (size_t)b*Lc*Dc + (size_t)l0*Dc + d;
    #pragma unroll
    for (int o = 0; o < T; ++o) {
        float acc = bv;
        #pragma unroll
        for (int k = 0; k < CKc; ++k) acc = fmaf(win[o+k], wt[k], acc);
        out[obase + (size_t)o*Dc] = __float2bfloat16(siluf_(acc));
    }
}

extern "C" void kernel_launch(void* const* d_in, const int* in_sizes, int n_in,
                              void* d_out, int out_size, void* d_ws, size_t ws_size,
                              hipStream_t stream) {
    const float* x      = (const float*)d_in[0];
    const float* ln_g   = (const float*)d_in[1];
    const float* ln_b   = (const float*)d_in[2];
    const float* W_in   = (const float*)d_in[3];
    const float* conv_w = (const float*)d_in[4];
    const float* conv_b = (const float*)d_in[5];
    const float* W_x    = (const float*)d_in[6];
    const float* W_dt   = (const float*)d_in[7];
    const float* b_dt   = (const float*)d_in[8];
    const float* A_log  = (const float*)d_in[9];
    const float* Dp     = (const float*)d_in[10];
    const float* W_out  = (const float*)d_in[11];
    const float* cm_ln_g= (const float*)d_in[12];
    const float* cm_ln_b= (const float*)d_in[13];
    const float* pw1_w  = (const float*)d_in[14];
    const float* pw1_b  = (const float*)d_in[15];
    const float* dw_w   = (const float*)d_in[16];
    const float* dw_b   = (const float*)d_in[17];
    const float* pw2_w  = (const float*)d_in[18];
    const float* pw2_b  = (const float*)d_in[19];
    const float* ff_W1  = (const float*)d_in[20];
    const float* ff_b1  = (const float*)d_in[21];
    const float* ff_W2  = (const float*)d_in[22];
    const float* ff_b2  = (const float*)d_in[23];
    float* out = (float*)d_out;
    float* ws  = (float*)d_ws;

    // ---- workspace layout (float offsets), total 22,986,752 floats ~92 MB ----
    float* A_  = ws;                 // 4,194,304: xi f32 -> gemm4 partials (2M) -> P(2M)+H(2M) -> c2 (4M)
    float* A2_ = ws + 4194304;       // 4,194,304: z f32 -> glu (2M)
    float* B_  = ws + 8388608;       // 4,194,304: xc f32 -> g1_bf16
    float* C_  = ws + 12582912;      //   262,144: dbl f32
    float* D_  = ws + 12845056;      // 4,194,304: delta -> m (2M)
    float* F_  = ws + 17039360;      // 1,572,864: dbl_bf16 / c_bf16 / cc_bf16 / f_bf16
    float* H_  = ws + 18612224;      // 2,097,152: h_bf16 / xc_bf16 / y_bf16
    float* J_  = ws + 20709376;      // 2,277,376: transposed bf16 weights

    float* xi_buf  = A_;
    float* part_buf= A_;             // 8 x 262144 = 2,097,152 (gemm4 split-K partials)
    float* P_buf   = A_;             // 64*32768 = 2,097,152
    float* H_buf   = A_ + 2097152;
    float* c2_buf  = A_;
    float* z_buf   = A2_;
    float* glu_buf = A2_;
    float* xc_buf  = B_;
    bf16*  g1b     = (bf16*)B_;
    float* dbl_buf = C_;
    float* dl_buf  = D_;
    float* m_buf   = D_;
    bf16*  dblb    = (bf16*)F_;
    bf16*  cb      = (bf16*)F_;
    bf16*  ccb     = (bf16*)F_;
    bf16*  fb      = (bf16*)F_;
    bf16*  hb      = (bf16*)H_;
    bf16*  xcb     = (bf16*)H_;
    bf16*  yb      = (bf16*)H_;
    float* f_buf   = out;            // f lives in d_out; GEMM15 reads it as residual

    bf16* Jw = (bf16*)J_;
    bf16* Win_t  = Jw;               // 2048 x 512
    bf16* Wx_t   = Jw + 1048576;     //   64 x 1024
    bf16* Wdt_t  = Jw + 1114112;     // 1024 x 32
    bf16* Wout_t = Jw + 1146880;     //  512 x 1024
    bf16* pw1_t  = Jw + 1671168;     // 1024 x 512
    bf16* pw2_t  = Jw + 2195456;     //  512 x 512
    bf16* ffW1_t = Jw + 2457600;     // 2048 x 512
    bf16* ffW2_t = Jw + 3506176;     //  512 x 2048

    const int M = Mrows;
    dim3 tw(32,8);

    // 0. weight transposes (f32 KxN -> bf16 NxK)
    wtrans<<<dim3(2048/32, 512/32), tw, 0, stream>>>(W_in,  Win_t,  512,  2048);
    wtrans<<<dim3(  64/32,1024/32), tw, 0, stream>>>(W_x,   Wx_t,   1024, 64);
    wtrans<<<dim3(1024/32,  32/32), tw, 0, stream>>>(W_dt,  Wdt_t,  32,   1024);
    wtrans<<<dim3( 512/32,1024/32), tw, 0, stream>>>(W_out, Wout_t, 1024, 512);
    wtrans<<<dim3(1024/32, 512/32), tw, 0, stream>>>(pw1_w, pw1_t,  512,  1024);
    wtrans<<<dim3( 512/32, 512/32), tw, 0, stream>>>(pw2_w, pw2_t,  512,  512);
    wtrans<<<dim3(2048/32, 512/32), tw, 0, stream>>>(ff_W1, ffW1_t, 512,  2048);
    wtrans<<<dim3( 512/32,2048/32), tw, 0, stream>>>(ff_W2, ffW2_t, 2048, 512);

    // 1. h = LN(x) -> bf16
    ln_kernel<false,true><<<M, 256, 0, stream>>>(x, ln_g, ln_b, nullptr, hb, Dc);
    // 2a. xi = h @ W_in[:, :DI]   2b. z = h @ W_in[:, DI:]
    mgemm<64,64,1,0,false,false,true,false><<<dim3(1024/64, M/64), 256, 0, stream>>>(
        hb, Dc, Win_t, nullptr, nullptr, xi_buf, nullptr, M, DIc, Dc);
    mgemm<64,64,1,0,false,false,true,false><<<dim3(1024/64, M/64), 256, 0, stream>>>(
        hb, Dc, Win_t + (size_t)DIc*Dc, nullptr, nullptr, z_buf, nullptr, M, DIc, Dc);
    // 3. xc = silu(causal dwconv(xi)) -> f32 + bf16   (sliding window, T=16)
    causal_conv_silu<16><<<dim3(DIc/256, Bc, Lc/16), 256, 0, stream>>>(xi_buf, conv_w, conv_b, xc_buf, xcb);
    // 4. dbl = xc @ W_x  (split-K=8 partials -> combine -> f32 + bf16)
    mgemm<64,64,8,0,false,false,true,false><<<dim3(64/64, M/64, 8), 256, 0, stream>>>(
        xcb, DIc, Wx_t, nullptr, nullptr, part_buf, nullptr, M, 64, DIc);
    splitk_combine<<<(M*64+255)/256, 256, 0, stream>>>(part_buf, dbl_buf, dblb, M*64, 8);
    // 5. delta = softplus(dt @ W_dt + b_dt) -> f32
    mgemm<64,64,1,1,true,false,true,false><<<dim3(1024/64, M/64), 256, 0, stream>>>(
        dblb, 64, Wdt_t, b_dt, nullptr, dl_buf, nullptr, M, DIc, Rc);
    // 6. chunked selective scan -> y (bf16)
    scan_pass1<<<512, 256, 0, stream>>>(dl_buf, xc_buf, dbl_buf, A_log, P_buf, H_buf);
    scan_combine<<<128, 256, 0, stream>>>(P_buf, H_buf);
    scan_pass3<<<512, 256, 0, stream>>>(dl_buf, xc_buf, dbl_buf, z_buf, A_log, Dp, P_buf, yb);
    // 7. m = y @ W_out -> f32
    mgemm<64,64,1,0,false,false,true,false><<<dim3(512/64, M/64), 256, 0, stream>>>(
        yb, DIc, Wout_t, nullptr, nullptr, m_buf, nullptr, M, Dc, DIc);
    // 8. c = LN(m, cm) -> bf16
    ln_kernel<false,true><<<M, 256, 0, stream>>>(m_buf, cm_ln_g, cm_ln_b, nullptr, cb, Dc);
    // 9. c2 = c @ pw1 + b -> f32
    mgemm<64,64,1,0,true,false,true,false><<<dim3(1024/64, M/64), 256, 0, stream>>>(
        cb, Dc, pw1_t, pw1_b, nullptr, c2_buf, nullptr, M, 2*Dc, Dc);
    // 10. GLU -> f32
    glu_kernel<<<(M*Dc+255)/256, 256, 0, stream>>>(c2_buf, glu_buf);
    // 11. symmetric dwconv CK=31 + silu -> bf16   (sliding window, T=16)
    sym_conv_silu<16><<<dim3(Dc/256, Bc, Lc/16), 256, 0, stream>>>(glu_buf, dw_w, dw_b, ccb);
    // 12. m = m + (cconv @ pw2 + b) -> f32 (in place)
    mgemm<64,64,1,0,true,true,true,false><<<dim3(512/64, M/64), 256, 0, stream>>>(
        ccb, Dc, pw2_t, pw2_b, m_buf, m_buf, nullptr, M, Dc, Dc);
    // 13. f = LN(m, ln) -> d_out (f32) + bf16
    ln_kernel<true,true><<<M, 256, 0, stream>>>(m_buf, ln_g, ln_b, f_buf, fb, Dc);
    // 14. g1 = gelu(f @ ff_W1 + b1) -> bf16
    mgemm<64,64,1,2,true,false,false,true><<<dim3(2048/64, M/64), 256, 0, stream>>>(
        fb, Dc, ffW1_t, ff_b1, nullptr, nullptr, g1b, M, DFFc, Dc);
    // 15. out = f + g1 @ ff_W2 + b2 -> d_out (in place: res tile == written tile)
    mgemm<64,64,1,0,true,true,true,false><<<dim3(512/64, M/64), 256, 0, stream>>>(
        g1b, DFFc, ffW2_t, ff_b2, f_buf, out, nullptr, M, Dc, DFFc);
}

// Round 8
// 251.024 us; speedup vs baseline: 12.4354x; 1.0397x over previous
//
#include <hip/hip_runtime.h>
#include <hip/hip_bf16.h>
#include <math.h>

// Problem constants
#define Bc   2
#define Lc   2048
#define Dc   512
#define DIc  1024
#define Nc   16
#define Kc   4
#define Rc   32
#define CKc  31
#define DFFc 2048
#define Mrows (Bc*Lc)   // 4096
#define CHUNK  32
#define NCHUNK 64

typedef __hip_bfloat16 bf16;
typedef short bf16x8 __attribute__((ext_vector_type(8)));
typedef float f32x4  __attribute__((ext_vector_type(4)));

__device__ __forceinline__ float sigmoidf_(float x){ return 1.f/(1.f+expf(-x)); }
__device__ __forceinline__ float siluf_(float x){ return x*sigmoidf_(x); }
__device__ __forceinline__ float softplusf_(float x){ return fmaxf(x,0.f)+log1pf(expf(-fabsf(x))); }
__device__ __forceinline__ float geluf_(float x){
    float x3 = x*x*x;
    return 0.5f*x*(1.f+tanhf(0.7978845608028654f*(x+0.044715f*x3)));
}

// async global -> LDS, 16 bytes/lane; lptr is wave-uniform base (HW adds lane*16)
__device__ __forceinline__ void gload16(const void* g, void* l) {
    __builtin_amdgcn_global_load_lds((const __attribute__((address_space(1))) void*)g,
                                     (__attribute__((address_space(3))) void*)l, 16, 0, 0);
}

// ---------------- LayerNorm (one block per row, D=512); optional f32/bf16 outs ----------------
template<bool WF, bool WB>
__global__ void ln_kernel(const float* __restrict__ in, const float* __restrict__ g,
                          const float* __restrict__ bb, float* __restrict__ outf,
                          bf16* __restrict__ outb, int D) {
    int row = blockIdx.x;
    const float* x = in + (size_t)row * D;
    float s = 0.f, s2 = 0.f;
    for (int i = threadIdx.x; i < D; i += blockDim.x) { float v = x[i]; s += v; s2 += v*v; }
    #pragma unroll
    for (int off = 32; off; off >>= 1) { s += __shfl_down(s, off); s2 += __shfl_down(s2, off); }
    __shared__ float sh[2][4];
    int wave = threadIdx.x >> 6, lane = threadIdx.x & 63;
    if (lane == 0) { sh[0][wave] = s; sh[1][wave] = s2; }
    __syncthreads();
    if (threadIdx.x == 0) {
        float ts = 0.f, ts2 = 0.f;
        int nw = blockDim.x >> 6;
        for (int w = 0; w < nw; ++w) { ts += sh[0][w]; ts2 += sh[1][w]; }
        sh[0][0] = ts; sh[1][0] = ts2;
    }
    __syncthreads();
    float mean = sh[0][0] / D;
    float var  = sh[1][0] / D - mean*mean;
    float rstd = rsqrtf(var + 1e-5f);
    for (int i = threadIdx.x; i < D; i += blockDim.x) {
        float v = (x[i]-mean)*rstd*g[i] + bb[i];
        if (WF) outf[(size_t)row*D + i] = v;
        if (WB) outb[(size_t)row*D + i] = __float2bfloat16(v);
    }
}

// ---------------- merged weight transpose+cast: 8 weights, one launch ----------------
struct WtPack {
    const float* W[8];
    bf16* Wt[8];
    int K[8];
    int N[8];
    int start[9];   // cumulative tile counts
};

__global__ void wtrans_all(WtPack p) {
    __shared__ float t[32][33];
    int tb = blockIdx.x;
    int wi = 0;
    #pragma unroll
    for (int i = 0; i < 7; ++i) if (tb >= p.start[i+1]) wi = i+1;
    int lt = tb - p.start[wi];
    int K = p.K[wi], N = p.N[wi];
    int ntx = N >> 5;
    int bx = lt % ntx, by = lt / ntx;
    const float* W = p.W[wi];
    bf16* Wt = p.Wt[wi];
    int tx = threadIdx.x, ty = threadIdx.y;   // 32 x 8
    #pragma unroll
    for (int i = 0; i < 32; i += 8)
        t[ty+i][tx] = W[(size_t)(by*32+ty+i)*N + bx*32+tx];
    __syncthreads();
    #pragma unroll
    for (int i = 0; i < 32; i += 8)
        Wt[(size_t)(bx*32+ty+i)*K + by*32+tx] = __float2bfloat16(t[tx][ty+i]);
}

// ---------------- bf16 MFMA GEMM, 64x64 tile, 2-phase dbuf + global_load_lds + XOR swizzle ----------------
// A: M x K bf16 (row stride lda), Wt: N x K bf16. out = act(A@Wt^T + bias) (+res).
// SPLITK>1: grid.z splits K; raw fp32 partials to outf + z*M*N.
// ZSEL=1: grid.z selects weight-half (Wt += z*N*K) and output-half (outf += z*M*N).
template<int BM, int BN, int SPLITK, int ZSEL, int ACT, bool BIAS, bool RES, bool WF32, bool WBF16>
__global__ __launch_bounds__(256) void mgemm(const bf16* __restrict__ A, int lda,
                                             const bf16* __restrict__ Wt,
                                             const float* __restrict__ bias,
                                             const float* __restrict__ res,
                                             float* __restrict__ outf,
                                             bf16* __restrict__ outb,
                                             int M, int N, int K) {
    constexpr int BK = 32;
    constexpr int WM = BM/2, WN = BN/2;       // per-wave tile (2x2 wave grid)
    constexpr int AM = WM/16, AN = WN/16;     // frags per wave
    constexpr int AISS = BM/64, BISS = BN/64; // 1KB staging issues per wave
    __shared__ __align__(16) bf16 As[2][BM*BK];
    __shared__ __align__(16) bf16 Bs[2][BN*BK];
    const int tid  = threadIdx.x;
    const int wave = tid >> 6, lane = tid & 63;
    const int r16  = lane & 15, kb = lane >> 4;
    // bijective XCD swizzle on flattened (x,y) block id (nwg % 8 == 0 for all launches here)
    const int gx = gridDim.x;
    const int nwg = gx*gridDim.y;
    const int id  = blockIdx.y*gx + blockIdx.x;
    const int sid = (id & 7)*(nwg >> 3) + (id >> 3);
    const int bm = (sid / gx)*BM, bn = (sid % gx)*BN;
    const int wm = (wave>>1)*WM, wn = (wave&1)*WN;
    const bf16* Wp = Wt;
    float* outfp = outf;
    if (ZSEL) { Wp += (size_t)blockIdx.z*N*K; outfp += (size_t)blockIdx.z*M*N; }
    const int Keff = K / SPLITK;
    const int kz0  = (SPLITK > 1) ? blockIdx.z * Keff : 0;
    f32x4 acc[AM][AN] = {};
    const int nt = Keff / BK;

    // stage tile kt into buffer buf (async)
    auto stage = [&](int buf, int kt) {
        #pragma unroll
        for (int it = 0; it < AISS; ++it) {
            int base = (wave*AISS + it) << 10;          // wave-uniform byte base
            int Lb   = base + (lane << 4);              // this lane's dest byte
            int row  = Lb >> 6;
            int gch  = ((Lb >> 4) & 3) ^ (row & 3);     // inverse swizzle on source
            gload16(A + (size_t)(bm + row)*lda + kz0 + kt*BK + gch*8, (char*)As[buf] + base);
        }
        #pragma unroll
        for (int it = 0; it < BISS; ++it) {
            int base = (wave*BISS + it) << 10;
            int Lb   = base + (lane << 4);
            int row  = Lb >> 6;
            int gch  = ((Lb >> 4) & 3) ^ (row & 3);
            gload16(Wp + (size_t)(bn + row)*K + kz0 + kt*BK + gch*8, (char*)Bs[buf] + base);
        }
    };

    stage(0, 0);
    __syncthreads();
    for (int t = 0; t < nt; ++t) {
        int cur = t & 1;
        if (t + 1 < nt) stage(cur ^ 1, t + 1);
        bf16x8 af[AM], bfr[AN];
        #pragma unroll
        for (int mi = 0; mi < AM; ++mi) {
            int r = wm + mi*16 + r16;
            af[mi] = *(const bf16x8*)((const char*)As[cur] + r*64 + ((kb ^ (r & 3)) << 4));
        }
        #pragma unroll
        for (int ni = 0; ni < AN; ++ni) {
            int r = wn + ni*16 + r16;
            bfr[ni] = *(const bf16x8*)((const char*)Bs[cur] + r*64 + ((kb ^ (r & 3)) << 4));
        }
        #pragma unroll
        for (int mi = 0; mi < AM; ++mi)
            #pragma unroll
            for (int ni = 0; ni < AN; ++ni)
                acc[mi][ni] = __builtin_amdgcn_mfma_f32_16x16x32_bf16(af[mi], bfr[ni], acc[mi][ni], 0, 0, 0);
        __syncthreads();   // drains stage(t+1) DMA + all waves done reading buf[cur]
    }

    // epilogue: C/D map col=lane&15, row=(lane>>4)*4+r
    #pragma unroll
    for (int mi = 0; mi < AM; ++mi) {
        #pragma unroll
        for (int ni = 0; ni < AN; ++ni) {
            #pragma unroll
            for (int r = 0; r < 4; ++r) {
                int grow = bm + wm + mi*16 + kb*4 + r;
                int gcol = bn + wn + ni*16 + r16;
                float v = acc[mi][ni][r];
                if (SPLITK > 1) {
                    outf[(size_t)blockIdx.z*M*N + (size_t)grow*N + gcol] = v;
                } else {
                    if (BIAS) v += bias[gcol];
                    if (ACT == 1) v = softplusf_(v);
                    else if (ACT == 2) v = geluf_(v);
                    if (RES) v += res[(size_t)grow*N + gcol];
                    if (WF32)  outfp[(size_t)grow*N + gcol] = v;
                    if (WBF16) outb[(size_t)grow*N + gcol] = __float2bfloat16(v);
                }
            }
        }
    }
}

// sum SPLITK partials -> f32 + bf16
__global__ void splitk_combine(const float* __restrict__ part, float* __restrict__ outf,
                               bf16* __restrict__ outb, int n, int parts) {
    int i = blockIdx.x*256 + threadIdx.x;
    if (i >= n) return;
    float s = 0.f;
    for (int p = 0; p < parts; ++p) s += part[(size_t)p*n + i];
    outf[i] = s;
    outb[i] = __float2bfloat16(s);
}

// ---------------- causal depthwise conv K=4 + silu -> bf16 only, sliding-window regs ----------------
template<int T>
__global__ __launch_bounds__(256) void causal_conv_silu(const float* __restrict__ xi, const float* __restrict__ w,
                                                        const float* __restrict__ bias,
                                                        bf16* __restrict__ xcb) {
    int d  = blockIdx.x*256 + threadIdx.x;
    int b  = blockIdx.y;
    int l0 = blockIdx.z*T;
    const float* src = xi + (size_t)b*Lc*DIc + d;
    float wt[Kc];
    #pragma unroll
    for (int k = 0; k < Kc; ++k) wt[k] = w[d*Kc + k];
    float win[T + Kc - 1];
    #pragma unroll
    for (int i = 0; i < T + Kc - 1; ++i) {
        int li = l0 - (Kc-1) + i;
        win[i] = (li >= 0) ? src[(size_t)li*DIc] : 0.f;   // li < Lc guaranteed
    }
    float bv = bias[d];
    size_t obase = (size_t)b*Lc*DIc + (size_t)l0*DIc + d;
    #pragma unroll
    for (int o = 0; o < T; ++o) {
        float acc = bv;
        #pragma unroll
        for (int k = 0; k < Kc; ++k) acc = fmaf(win[o+k], wt[k], acc);
        xcb[obase + (size_t)o*DIc] = __float2bfloat16(siluf_(acc));
    }
}

// ---------------- chunked selective scan, thread-per-channel, 16 states in registers ----------------
__global__ __launch_bounds__(256) void scan_pass1(const float* __restrict__ delta, const bf16* __restrict__ xc,
                                                  const float* __restrict__ dbl, const float* __restrict__ A_log,
                                                  float* __restrict__ P, float* __restrict__ H) {
    int dgroup = blockIdx.x & 3;
    int bc = blockIdx.x >> 2;           // 0..127
    int b = bc & 1, chunk = bc >> 1;    // chunk 0..63
    int d = dgroup*256 + threadIdx.x;
    float Av[16];
    #pragma unroll
    for (int j = 0; j < 4; ++j) {
        f32x4 v = *(const f32x4*)(&A_log[d*16 + 4*j]);
        #pragma unroll
        for (int q = 0; q < 4; ++q) Av[4*j+q] = -__expf(v[q]);
    }
    float h[16], Pl[16];
    #pragma unroll
    for (int n = 0; n < 16; ++n) { h[n] = 0.f; Pl[n] = 1.f; }
    size_t row0 = (size_t)b*Lc + (size_t)chunk*CHUNK;
    for (int i = 0; i < CHUNK; ++i) {
        size_t rowi = row0 + i;
        float dv  = delta[rowi*DIc + d];
        float xcv = __bfloat162float(xc[rowi*DIc + d]);
        float dxc = dv*xcv;
        f32x4 B0 = *(const f32x4*)(&dbl[rowi*64 + Rc + 0]);
        f32x4 B1 = *(const f32x4*)(&dbl[rowi*64 + Rc + 4]);
        f32x4 B2 = *(const f32x4*)(&dbl[rowi*64 + Rc + 8]);
        f32x4 B3 = *(const f32x4*)(&dbl[rowi*64 + Rc + 12]);
        float Bv[16];
        #pragma unroll
        for (int q = 0; q < 4; ++q) { Bv[q]=B0[q]; Bv[4+q]=B1[q]; Bv[8+q]=B2[q]; Bv[12+q]=B3[q]; }
        #pragma unroll
        for (int n = 0; n < 16; ++n) {
            float a = __expf(dv*Av[n]);
            h[n] = fmaf(a, h[n], dxc*Bv[n]);
            Pl[n] *= a;
        }
    }
    size_t pidx = ((size_t)chunk*2048 + (size_t)b*DIc + d) * 16;
    #pragma unroll
    for (int j = 0; j < 4; ++j) {
        f32x4 vp, vh;
        #pragma unroll
        for (int q = 0; q < 4; ++q) { vp[q] = Pl[4*j+q]; vh[q] = h[4*j+q]; }
        *(f32x4*)(&P[pidx + 4*j]) = vp;
        *(f32x4*)(&H[pidx + 4*j]) = vh;
    }
}

// Serial combine across chunks; writes prefix state (hstart) back into P in place.
__global__ void scan_combine(float* __restrict__ P, const float* __restrict__ H) {
    int t = blockIdx.x*blockDim.x + threadIdx.x;  // 0..32767 = (b*DI+d)*16+n
    float h = 0.f;
    #pragma unroll
    for (int c = 0; c < NCHUNK; ++c) {
        size_t idx = (size_t)c*32768 + t;
        float Pv = P[idx], Hv = H[idx];
        P[idx] = h;                 // hstart for chunk c
        h = fmaf(Pv, h, Hv);
    }
}

// Pass 3: re-scan from prefix; reads xc (bf16), writes y (bf16) IN PLACE over xc
// (safe: each element read-then-written by its owning thread; pass1 already done).
__global__ __launch_bounds__(256) void scan_pass3(const float* __restrict__ delta, const bf16* __restrict__ xc,
                                                  const float* __restrict__ dbl, const float* __restrict__ z,
                                                  const float* __restrict__ A_log, const float* __restrict__ Dp,
                                                  const float* __restrict__ hstart, bf16* __restrict__ y) {
    int dgroup = blockIdx.x & 3;
    int bc = blockIdx.x >> 2;
    int b = bc & 1, chunk = bc >> 1;
    int d = dgroup*256 + threadIdx.x;
    float Av[16];
    #pragma unroll
    for (int j = 0; j < 4; ++j) {
        f32x4 v = *(const f32x4*)(&A_log[d*16 + 4*j]);
        #pragma unroll
        for (int q = 0; q < 4; ++q) Av[4*j+q] = -__expf(v[q]);
    }
    float Dv = Dp[d];
    float h[16];
    size_t pidx = ((size_t)chunk*2048 + (size_t)b*DIc + d) * 16;
    #pragma unroll
    for (int j = 0; j < 4; ++j) {
        f32x4 v = *(const f32x4*)(&hstart[pidx + 4*j]);
        #pragma unroll
        for (int q = 0; q < 4; ++q) h[4*j+q] = v[q];
    }
    size_t row0 = (size_t)b*Lc + (size_t)chunk*CHUNK;
    for (int i = 0; i < CHUNK; ++i) {
        size_t rowi = row0 + i;
        float dv  = delta[rowi*DIc + d];
        float xcv = __bfloat162float(xc[rowi*DIc + d]);
        float dxc = dv*xcv;
        f32x4 B0 = *(const f32x4*)(&dbl[rowi*64 + Rc + 0]);
        f32x4 B1 = *(const f32x4*)(&dbl[rowi*64 + Rc + 4]);
        f32x4 B2 = *(const f32x4*)(&dbl[rowi*64 + Rc + 8]);
        f32x4 B3 = *(const f32x4*)(&dbl[rowi*64 + Rc + 12]);
        f32x4 C0 = *(const f32x4*)(&dbl[rowi*64 + Rc + Nc + 0]);
        f32x4 C1 = *(const f32x4*)(&dbl[rowi*64 + Rc + Nc + 4]);
        f32x4 C2 = *(const f32x4*)(&dbl[rowi*64 + Rc + Nc + 8]);
        f32x4 C3 = *(const f32x4*)(&dbl[rowi*64 + Rc + Nc + 12]);
        float Bv[16], Cv[16];
        #pragma unroll
        for (int q = 0; q < 4; ++q) {
            Bv[q]=B0[q]; Bv[4+q]=B1[q]; Bv[8+q]=B2[q]; Bv[12+q]=B3[q];
            Cv[q]=C0[q]; Cv[4+q]=C1[q]; Cv[8+q]=C2[q]; Cv[12+q]=C3[q];
        }
        float s0=0.f, s1=0.f, s2=0.f, s3=0.f;
        #pragma unroll
        for (int n = 0; n < 16; ++n) {
            float a = __expf(dv*Av[n]);
            h[n] = fmaf(a, h[n], dxc*Bv[n]);
        }
        #pragma unroll
        for (int j = 0; j < 4; ++j) {
            s0 = fmaf(h[4*j+0], Cv[4*j+0], s0);
            s1 = fmaf(h[4*j+1], Cv[4*j+1], s1);
            s2 = fmaf(h[4*j+2], Cv[4*j+2], s2);
            s3 = fmaf(h[4*j+3], Cv[4*j+3], s3);
        }
        float contrib = (s0+s1)+(s2+s3);
        float zv = z[rowi*DIc + d];
        y[rowi*DIc + d] = __float2bfloat16((contrib + Dv*xcv) * siluf_(zv));
    }
}

// ---------------- fused GLU + symmetric depthwise conv CK=31 + silu -> bf16 ----------------
// Reads c2 (M x 1024: [a | g]); window element = a*sigmoid(g); then 31-tap conv + silu.
template<int T>
__global__ __launch_bounds__(256) void sym_conv_glu_silu(const float* __restrict__ c2, const float* __restrict__ w,
                                                         const float* __restrict__ bias, bf16* __restrict__ out) {
    int d  = blockIdx.x*256 + threadIdx.x;   // 0..511
    int b  = blockIdx.y;
    int l0 = blockIdx.z*T;
    const float* base = c2 + (size_t)b*Lc*(2*Dc) + d;
    float wt[CKc];
    #pragma unroll
    for (int k = 0; k < CKc; ++k) wt[k] = w[d*CKc + k];
    constexpr int HALF = (CKc-1)/2;   // 15
    float win[T + CKc - 1];
    #pragma unroll
    for (int i = 0; i < T + CKc - 1; ++i) {
        int li = l0 - HALF + i;
        if (li >= 0 && li < Lc) {
            float a = base[(size_t)li*(2*Dc)];
            float g = base[(size_t)li*(2*Dc) + Dc];
            win[i] = a * sigmoidf_(g);
        } else win[i] = 0.f;
    }
    float bv = bias[d];
    size_t obase = (size_t)b*Lc*Dc + (size_t)l0*Dc + d;
    #pragma unroll
    for (int o = 0; o < T; ++o) {
        float acc = bv;
        #pragma unroll
        for (int k = 0; k < CKc; ++k) acc = fmaf(win[o+k], wt[k], acc);
        out[obase + (size_t)o*Dc] = __float2bfloat16(siluf_(acc));
    }
}

extern "C" void kernel_launch(void* const* d_in, const int* in_sizes, int n_in,
                              void* d_out, int out_size, void* d_ws, size_t ws_size,
                              hipStream_t stream) {
    const float* x      = (const float*)d_in[0];
    const float* ln_g   = (const float*)d_in[1];
    const float* ln_b   = (const float*)d_in[2];
    const float* W_in   = (const float*)d_in[3];
    const float* conv_w = (const float*)d_in[4];
    const float* conv_b = (const float*)d_in[5];
    const float* W_x    = (const float*)d_in[6];
    const float* W_dt   = (const float*)d_in[7];
    const float* b_dt   = (const float*)d_in[8];
    const float* A_log  = (const float*)d_in[9];
    const float* Dp     = (const float*)d_in[10];
    const float* W_out  = (const float*)d_in[11];
    const float* cm_ln_g= (const float*)d_in[12];
    const float* cm_ln_b= (const float*)d_in[13];
    const float* pw1_w  = (const float*)d_in[14];
    const float* pw1_b  = (const float*)d_in[15];
    const float* dw_w   = (const float*)d_in[16];
    const float* dw_b   = (const float*)d_in[17];
    const float* pw2_w  = (const float*)d_in[18];
    const float* pw2_b  = (const float*)d_in[19];
    const float* ff_W1  = (const float*)d_in[20];
    const float* ff_b1  = (const float*)d_in[21];
    const float* ff_W2  = (const float*)d_in[22];
    const float* ff_b2  = (const float*)d_in[23];
    float* out = (float*)d_out;
    float* ws  = (float*)d_ws;

    // ---- workspace layout (float offsets), total 22,986,752 floats ~92 MB ----
    float* A_  = ws;                 // 4,194,304: xi f32 -> gemm4 partials/P(2M)+H(2M) -> c2 (4M)
    float* A2_ = ws + 4194304;       // 4,194,304: z f32  (contiguous after A_ for ZSEL GEMM2)
    float* B_  = ws + 8388608;       // 4,194,304: g1_bf16
    float* C_  = ws + 12582912;      //   262,144: dbl f32
    float* D_  = ws + 12845056;      // 4,194,304: delta -> m (2M)
    float* F_  = ws + 17039360;      // 1,572,864: dbl_bf16 / c_bf16 / cc_bf16 / f_bf16
    float* H_  = ws + 18612224;      // 2,097,152: h_bf16 / xc_bf16 / y_bf16 (in place)
    float* J_  = ws + 20709376;      // 2,277,376: transposed bf16 weights

    float* xi_buf  = A_;             // z_buf = A_ + M*DIc (= A2_), via ZSEL
    float* part_buf= A_;             // 8 x 262144 (gemm4 split-K partials)
    float* P_buf   = A_;             // 64*32768 = 2,097,152
    float* H_buf   = A_ + 2097152;
    float* c2_buf  = A_;
    float* z_buf   = A2_;
    bf16*  g1b     = (bf16*)B_;
    float* dbl_buf = C_;
    float* dl_buf  = D_;
    float* m_buf   = D_;
    bf16*  dblb    = (bf16*)F_;
    bf16*  cb      = (bf16*)F_;
    bf16*  ccb     = (bf16*)F_;
    bf16*  fb      = (bf16*)F_;
    bf16*  hb      = (bf16*)H_;
    bf16*  xcb     = (bf16*)H_;
    bf16*  yb      = (bf16*)H_;      // overwrites xcb in-place during scan_pass3
    float* f_buf   = out;            // f lives in d_out; GEMM15 reads it as residual

    bf16* Jw = (bf16*)J_;
    bf16* Win_t  = Jw;               // 2048 x 512
    bf16* Wx_t   = Jw + 1048576;     //   64 x 1024
    bf16* Wdt_t  = Jw + 1114112;     // 1024 x 32
    bf16* Wout_t = Jw + 1146880;     //  512 x 1024
    bf16* pw1_t  = Jw + 1671168;     // 1024 x 512
    bf16* pw2_t  = Jw + 2195456;     //  512 x 512
    bf16* ffW1_t = Jw + 2457600;     // 2048 x 512
    bf16* ffW2_t = Jw + 3506176;     //  512 x 2048

    const int M = Mrows;

    // 0. all weight transposes in one launch
    {
        WtPack p;
        const float* Ws[8] = {W_in, W_x, W_dt, W_out, pw1_w, pw2_w, ff_W1, ff_W2};
        bf16* Ts[8] = {Win_t, Wx_t, Wdt_t, Wout_t, pw1_t, pw2_t, ffW1_t, ffW2_t};
        int Ks[8] = {512, 1024, 32, 1024, 512, 512, 512, 2048};
        int Ns[8] = {2048, 64, 1024, 512, 1024, 512, 2048, 512};
        int acc = 0;
        for (int i = 0; i < 8; ++i) {
            p.W[i] = Ws[i]; p.Wt[i] = Ts[i]; p.K[i] = Ks[i]; p.N[i] = Ns[i];
            p.start[i] = acc;
            acc += (Ns[i]/32)*(Ks[i]/32);
        }
        p.start[8] = acc;   // 4448
        wtrans_all<<<acc, dim3(32,8), 0, stream>>>(p);
    }

    // 1. h = LN(x) -> bf16
    ln_kernel<false,true><<<M, 256, 0, stream>>>(x, ln_g, ln_b, nullptr, hb, Dc);
    // 2. xi = h @ W_in[:, :DI]; z = h @ W_in[:, DI:]  (one launch, grid.z=2)
    mgemm<64,64,1,1,0,false,false,true,false><<<dim3(1024/64, M/64, 2), 256, 0, stream>>>(
        hb, Dc, Win_t, nullptr, nullptr, xi_buf, nullptr, M, DIc, Dc);
    // 3. xc = silu(causal dwconv(xi)) -> bf16   (sliding window, T=16)
    causal_conv_silu<16><<<dim3(DIc/256, Bc, Lc/16), 256, 0, stream>>>(xi_buf, conv_w, conv_b, xcb);
    // 4. dbl = xc @ W_x  (split-K=8 partials -> combine -> f32 + bf16)
    mgemm<64,64,8,0,0,false,false,true,false><<<dim3(64/64, M/64, 8), 256, 0, stream>>>(
        xcb, DIc, Wx_t, nullptr, nullptr, part_buf, nullptr, M, 64, DIc);
    splitk_combine<<<(M*64+255)/256, 256, 0, stream>>>(part_buf, dbl_buf, dblb, M*64, 8);
    // 5. delta = softplus(dt @ W_dt + b_dt) -> f32
    mgemm<64,64,1,0,1,true,false,true,false><<<dim3(1024/64, M/64), 256, 0, stream>>>(
        dblb, 64, Wdt_t, b_dt, nullptr, dl_buf, nullptr, M, DIc, Rc);
    // 6. chunked selective scan -> y (bf16, in place over xcb)
    scan_pass1<<<512, 256, 0, stream>>>(dl_buf, xcb, dbl_buf, A_log, P_buf, H_buf);
    scan_combine<<<128, 256, 0, stream>>>(P_buf, H_buf);
    scan_pass3<<<512, 256, 0, stream>>>(dl_buf, xcb, dbl_buf, z_buf, A_log, Dp, P_buf, yb);
    // 7. m = y @ W_out -> f32
    mgemm<64,64,1,0,0,false,false,true,false><<<dim3(512/64, M/64), 256, 0, stream>>>(
        yb, DIc, Wout_t, nullptr, nullptr, m_buf, nullptr, M, Dc, DIc);
    // 8. c = LN(m, cm) -> bf16
    ln_kernel<false,true><<<M, 256, 0, stream>>>(m_buf, cm_ln_g, cm_ln_b, nullptr, cb, Dc);
    // 9. c2 = c @ pw1 + b -> f32
    mgemm<64,64,1,0,0,true,false,true,false><<<dim3(1024/64, M/64), 256, 0, stream>>>(
        cb, Dc, pw1_t, pw1_b, nullptr, c2_buf, nullptr, M, 2*Dc, Dc);
    // 10+11. GLU fused into symmetric dwconv CK=31 + silu -> bf16
    sym_conv_glu_silu<16><<<dim3(Dc/256, Bc, Lc/16), 256, 0, stream>>>(c2_buf, dw_w, dw_b, ccb);
    // 12. m = m + (cconv @ pw2 + b) -> f32 (in place)
    mgemm<64,64,1,0,0,true,true,true,false><<<dim3(512/64, M/64), 256, 0, stream>>>(
        ccb, Dc, pw2_t, pw2_b, m_buf, m_buf, nullptr, M, Dc, Dc);
    // 13. f = LN(m, ln) -> d_out (f32) + bf16
    ln_kernel<true,true><<<M, 256, 0, stream>>>(m_buf, ln_g, ln_b, f_buf, fb, Dc);
    // 14. g1 = gelu(f @ ff_W1 + b1) -> bf16
    mgemm<64,64,1,0,2,true,false,false,true><<<dim3(2048/64, M/64), 256, 0, stream>>>(
        fb, Dc, ffW1_t, ff_b1, nullptr, nullptr, g1b, M, DFFc, Dc);
    // 15. out = f + g1 @ ff_W2 + b2 -> d_out (in place: res tile == written tile)
    mgemm<64,64,1,0,0,true,true,true,false><<<dim3(512/64, M/64), 256, 0, stream>>>(
        g1b, DFFc, ffW2_t, ff_b2, f_buf, out, nullptr, M, Dc, DFFc);
}